// Round 5
// baseline (608.094 us; speedup 1.0000x reference)
//
#include <hip/hip_runtime.h>
#include <hip/hip_bf16.h>
#include <cstdint>

// I/O is FP32. Derivation: c=DT=0.1, d=1+DT/EPS=11; layer out = (-u,-v):
//   V = [vr | rhsu] @ Bcat^T, Bcat = [Minv | 0.1*(Minv W^T)] (1024x2048),
//   u_raw = 0.1 V W^T = AC @ Ccat^T, Ccat = 0.1*W@Bcat = [0.1*P | 0.01*P@W^T],
//   P = W@Minv;  un = u_raw - u_in - 0.1 b;  AC_next = [10relu(un)-V | un+0.1b'],
//   Minv = (I - (0.01/11) W^T W)/11  (Neumann, trunc err ~1.5e-6).
// R11: dispatch-graph compaction (V-route reverted — ulayer was memory-bound):
//   (a) fused gemm_layer restored (79.4us known-good).
//   (b) gemm_z0m: bt<0> + the 3 Minv GEMMs in ONE dispatch (grid 8x88).
//       Minv goes to the transient region @128MB (NOT Bcat@18MB, which
//       aliases live xb during this dispatch).
//   (c) pp2: step67 (384 blocks) + Ccat-lo (192) in ONE dispatch with an
//       agent-scope atomic producer->consumer barrier; z6<3 producer blocks
//       also copy their Minv tile into Bcat-hi (xb dead by then).
//       Co-residency: 32KB LDS + launch_bounds(256,3) -> 768 slots >= 576.
//   Dispatches 10 -> 8 (+1 graph-safe memset for the counter).

typedef __bf16 bf16;
typedef __bf16 bf16x4 __attribute__((ext_vector_type(4)));
typedef __bf16 bf16x8 __attribute__((ext_vector_type(8)));
typedef float  f32x4  __attribute__((ext_vector_type(4)));

#define C_DT    0.1f
#define C_DTEPS 10.0f
#define C_DINV  (1.0f/11.0f)
#define C_MSC   (0.01f/121.0f)

__device__ __forceinline__ void async_load16(const bf16* g, bf16* l) {
    __builtin_amdgcn_global_load_lds(
        (__attribute__((address_space(1))) void*)(g),
        (__attribute__((address_space(3))) void*)(l),
        16, 0, 0);
}

// XCD-aware remap for (8,64) grids: per-XCD L2 working set ~ row-panel + B.
__device__ __forceinline__ void remap_block(int& bx, int& by) {
    if (gridDim.y == 64) {
        const int lin  = by * 8 + bx;
        const int xcd  = lin & 7;
        const int slot = lin >> 3;
        by = xcd * 8 + (slot & 7);
        bx = slot >> 3;
    }
}

// ---------------------------------------------------------------------------
// C = A @ B^T (A: MxK ld lda, B: NxK ld ldb, bf16). 128x128 tile, BK=32,
// double-buffered.
// EPI 5 ULAST: un=sgn*a-e0[m*ldf+n]-0.1*e1[n]; out_b1=hi(un); out_b2=lo(un)
// ---------------------------------------------------------------------------
template<int EPI>
__global__ __launch_bounds__(256, 3)
void gemm_bt(const bf16* __restrict__ A, const bf16* __restrict__ B,
             float* __restrict__ out_f,
             bf16* __restrict__ out_b1, bf16* __restrict__ out_b2,
             const float* __restrict__ e0, const float* __restrict__ e1,
             const float* __restrict__ e2,
             int M, int N, int K, int lda, int ldb,
             int ldf, int ld1, int ld2, float sgn,
             long zsA, long zsB, long zs1, long zs2)
{
    __shared__ __attribute__((aligned(16))) char smem[32768];
    bf16* sAe = (bf16*)smem;             // 2 x 4096 elements
    bf16* sBe = (bf16*)(smem + 16384);

    const int t    = threadIdx.x;
    const int wave = t >> 6;
    const int lane = t & 63;
    int bx = blockIdx.x, by = blockIdx.y;
    remap_block(bx, by);
    const long zb = blockIdx.z;
    A += zb * zsA;
    B += zb * zsB;
    if (out_b1) out_b1 += zb * zs1;
    if (out_b2) out_b2 += zb * zs2;

    const long row0 = (long)by * 128;
    const long col0 = (long)bx * 128;
    const int wr = wave >> 1, wc = wave & 1;

    f32x4 acc[4][4];
#pragma unroll
    for (int i = 0; i < 4; i++)
#pragma unroll
        for (int j = 0; j < 4; j++)
            acc[i][j] = f32x4{0.f, 0.f, 0.f, 0.f};

    const int  q  = t >> 2;
    const int  gp = ((t & 3) + 4 - ((q + (q >> 2)) & 3)) & 3;
    const bf16* gA = A + (row0 + q) * (long)lda + gp * 8;
    const bf16* gB = B + (col0 + q) * (long)ldb + gp * 8;

    const int l15  = lane & 15;
    const int fch  = ((lane >> 4) + l15 + (l15 >> 2)) & 3;
    const int aoff = (wr * 64 + l15) * 32 + fch * 8;
    const int boff = (wc * 64 + l15) * 32 + fch * 8;

    auto stage = [&](int buf, int k0) {
        bf16* dA = sAe + buf * 4096 + wave * 512;
        bf16* dB = sBe + buf * 4096 + wave * 512;
        async_load16(gA + k0,                     dA);
        async_load16(gA + 64 * (long)lda + k0,    dA + 2048);
        async_load16(gB + k0,                     dB);
        async_load16(gB + 64 * (long)ldb + k0,    dB + 2048);
    };

    const int nIter = K >> 5;
    stage(0, 0);
    __syncthreads();
    for (int k = 0; k < nIter; k++) {
        const int cur = k & 1;
        if (k + 1 < nIter) stage(cur ^ 1, (k + 1) << 5);

        bf16x8 af[4], bfv[4];
#pragma unroll
        for (int i = 0; i < 4; i++)
            af[i] = *(const bf16x8*)(sAe + cur * 4096 + aoff + i * 16 * 32);
#pragma unroll
        for (int j = 0; j < 4; j++)
            bfv[j] = *(const bf16x8*)(sBe + cur * 4096 + boff + j * 16 * 32);
#pragma unroll
        for (int i = 0; i < 4; i++)
#pragma unroll
            for (int j = 0; j < 4; j++)
                acc[i][j] = __builtin_amdgcn_mfma_f32_16x16x32_bf16(
                    af[i], bfv[j], acc[i][j], 0, 0, 0);

        __syncthreads();
    }

    float* epi = (float*)smem + wave * 1024;
    const int wbase = (lane >> 4) * 256 + (l15 >> 2) * 4 + (l15 & 3);

#pragma unroll
    for (int i = 0; i < 4; i++) {
#pragma unroll
        for (int j = 0; j < 4; j++)
#pragma unroll
            for (int r = 0; r < 4; r++)
                epi[wbase + r * 64 + 16 * j] = acc[i][j][r];

#pragma unroll
        for (int qq = 0; qq < 4; qq++) {
            const f32x4 a4 = ((const f32x4*)epi)[qq * 64 + lane];
            const long m = row0 + wr * 64 + i * 16 + qq * 4 + (lane >> 4);
            const long n = col0 + wc * 64 + 4 * l15;

            if (EPI == 5) {
                const f32x4 u0 = *(const f32x4*)(e0 + m * (long)ldf + n);
                const f32x4 b1 = *(const f32x4*)(e1 + n);
                bf16x4 hv, lv;
#pragma unroll
                for (int e = 0; e < 4; e++) {
                    float un = sgn * a4[e] - u0[e] - C_DT * b1[e];
                    bf16 h = (bf16)un;
                    hv[e] = h;
                    lv[e] = (bf16)(un - (float)h);
                }
                *(bf16x4*)(out_b1 + m * (long)ld1 + n) = hv;
                *(bf16x4*)(out_b2 + m * (long)ld2 + n) = lv;
            }
        }
    }
}

// ---------------------------------------------------------------------------
// Merged z0 + Minv dispatch. Grid (8, 88):
//   by < 64 : z0 = xb@Winb^T + b_in (K=2048, M=8192, XCD-remapped):
//             u=z0 fp32; ACa=[11relu(z0) | z0+0.1*b1].
//   by >= 64: zm=(by-64)>>3: C = Wt[zm]@Wt[zm]^T (K=1024);
//             Minv[zm] = (m==n?1/11:0) - C_MSC*C  (-> transient @128MB only;
//             Bcat aliases live xb and is filled by pp2).
// ---------------------------------------------------------------------------
__global__ __launch_bounds__(256, 3)
void gemm_z0m(const bf16* __restrict__ xb, const bf16* __restrict__ winb,
              const bf16* __restrict__ wtbf,
              float* __restrict__ u, bf16* __restrict__ ACa,
              bf16* __restrict__ Minv,
              const float* __restrict__ e1, const float* __restrict__ e2)
{
    __shared__ __attribute__((aligned(16))) char smem[32768];
    bf16* sAe = (bf16*)smem;
    bf16* sBe = (bf16*)(smem + 16384);

    const int t    = threadIdx.x;
    const int wave = t >> 6;
    const int lane = t & 63;
    const long M1v = 1024L * 1024;

    const bool mainp = (blockIdx.y < 64);
    int bx, by, nIter, zm = 0;
    long lda;
    const bf16 *Abase, *Bbase;
    if (mainp) {
        const int lin  = blockIdx.y * 8 + blockIdx.x;
        const int xcd  = lin & 7;
        const int slot = lin >> 3;
        by = xcd * 8 + (slot & 7);
        bx = slot >> 3;
        lda = 2048; nIter = 64;
        Abase = xb; Bbase = winb;
    } else {
        zm = (blockIdx.y - 64) >> 3;
        by = (blockIdx.y - 64) & 7;
        bx = blockIdx.x;
        lda = 1024; nIter = 32;
        Abase = wtbf + zm * M1v; Bbase = Abase;
    }
    const long row0 = (long)by * 128;
    const long col0 = (long)bx * 128;
    const int wr = wave >> 1, wc = wave & 1;

    f32x4 acc[4][4];
#pragma unroll
    for (int i = 0; i < 4; i++)
#pragma unroll
        for (int j = 0; j < 4; j++)
            acc[i][j] = f32x4{0.f, 0.f, 0.f, 0.f};

    const int  q  = t >> 2;
    const int  gp = ((t & 3) + 4 - ((q + (q >> 2)) & 3)) & 3;
    const bf16* gA = Abase + (row0 + q) * lda + gp * 8;
    const bf16* gB = Bbase + (col0 + q) * lda + gp * 8;

    const int l15  = lane & 15;
    const int fch  = ((lane >> 4) + l15 + (l15 >> 2)) & 3;
    const int aoff = (wr * 64 + l15) * 32 + fch * 8;
    const int boff = (wc * 64 + l15) * 32 + fch * 8;

    auto stage = [&](int buf, int k0) {
        bf16* dA = sAe + buf * 4096 + wave * 512;
        bf16* dB = sBe + buf * 4096 + wave * 512;
        async_load16(gA + k0,              dA);
        async_load16(gA + 64 * lda + k0,   dA + 2048);
        async_load16(gB + k0,              dB);
        async_load16(gB + 64 * lda + k0,   dB + 2048);
    };

    stage(0, 0);
    __syncthreads();
    for (int k = 0; k < nIter; k++) {
        const int cur = k & 1;
        if (k + 1 < nIter) stage(cur ^ 1, (k + 1) << 5);

        bf16x8 af[4], bfv[4];
#pragma unroll
        for (int i = 0; i < 4; i++)
            af[i] = *(const bf16x8*)(sAe + cur * 4096 + aoff + i * 16 * 32);
#pragma unroll
        for (int j = 0; j < 4; j++)
            bfv[j] = *(const bf16x8*)(sBe + cur * 4096 + boff + j * 16 * 32);
#pragma unroll
        for (int i = 0; i < 4; i++)
#pragma unroll
            for (int j = 0; j < 4; j++)
                acc[i][j] = __builtin_amdgcn_mfma_f32_16x16x32_bf16(
                    af[i], bfv[j], acc[i][j], 0, 0, 0);
        __syncthreads();
    }

    float* epi = (float*)smem + wave * 1024;
    const int wbase = (lane >> 4) * 256 + (l15 >> 2) * 4 + (l15 & 3);

#pragma unroll
    for (int i = 0; i < 4; i++) {
#pragma unroll
        for (int j = 0; j < 4; j++)
#pragma unroll
            for (int r = 0; r < 4; r++)
                epi[wbase + r * 64 + 16 * j] = acc[i][j][r];

#pragma unroll
        for (int qq = 0; qq < 4; qq++) {
            const f32x4 a4 = ((const f32x4*)epi)[qq * 64 + lane];
            const long m = row0 + wr * 64 + i * 16 + qq * 4 + (lane >> 4);
            const long n = col0 + wc * 64 + 4 * l15;

            if (mainp) {
                const f32x4 b1 = *(const f32x4*)(e1 + n);
                const f32x4 b2 = *(const f32x4*)(e2 + n);
                f32x4 tv; bf16x4 rv, hv;
#pragma unroll
                for (int e = 0; e < 4; e++) {
                    tv[e] = a4[e] + b1[e];
                    rv[e] = (bf16)(11.f * fmaxf(tv[e], 0.f));
                    hv[e] = (bf16)(tv[e] + C_DT * b2[e]);
                }
                *(f32x4*)(u + m * 1024 + n)           = tv;
                *(bf16x4*)(ACa + m * 2048 + n)        = rv;
                *(bf16x4*)(ACa + m * 2048 + 1024 + n) = hv;
            } else {
                bf16x4 ov;
#pragma unroll
                for (int e = 0; e < 4; e++)
                    ov[e] = (bf16)(((m == n + e) ? C_DINV : 0.f) - C_MSC * a4[e]);
                *(bf16x4*)(Minv + zm * M1v + m * 1024 + n) = ov;
            }
        }
    }
}

// ---------------------------------------------------------------------------
// pp2: remaining prep in one dispatch (576 blocks, co-resident:
// 32KB LDS + (256,3) -> 768 slots).
//   bid <  384 (producers): z6=bid>>6:
//     z6<3 : Bcat[z6][:,1024:] = 0.1*Minv[z6]@W[z6]^T; also copy its 128x128
//            Minv tile into Bcat[z6][:, :1024] (xb dead now).
//     z6>=3: P[zr] = W[zr]@Minv[zr]^T;  Ccat[zr][:, :1024] = 0.1*P.
//     Then release-increment ctr.
//   bid >= 384 (consumers): acquire-spin ctr==384, then
//     Ccat[zc][:,1024:] = 0.01*P[zc]@W[zc]^T.
// ---------------------------------------------------------------------------
__global__ __launch_bounds__(256, 3)
void pp2(const bf16* __restrict__ Minv, const bf16* __restrict__ Wbf,
         bf16* __restrict__ Bcat, bf16* __restrict__ Pmat,
         bf16* __restrict__ Ccat, unsigned int* __restrict__ ctr)
{
    __shared__ __attribute__((aligned(16))) char smem[32768];
    bf16* sAe = (bf16*)smem;
    bf16* sBe = (bf16*)(smem + 16384);

    const int bid  = blockIdx.x;
    const int t    = threadIdx.x;
    const int wave = t >> 6;
    const int lane = t & 63;
    const long M1v = 1024L * 1024;
    const bool prod = (bid < 384);

    const bf16 *A, *B;
    bf16 *o1, *o2 = nullptr;
    bf16 *bhi = nullptr;                // Bcat-hi copy target (z6<3 only)
    int ld1 = 2048, bx, by;
    float s1, s2 = C_DT;

    if (prod) {
        const int z6  = bid >> 6;
        const int idx = bid & 63;
        bx = idx & 7; by = idx >> 3;
        if (z6 < 3) {
            A = Minv + z6 * M1v; B = Wbf + z6 * M1v;
            o1 = Bcat + z6 * 2 * M1v + 1024; s1 = C_DT;
            bhi = Bcat + z6 * 2 * M1v;
        } else {
            const int zr = z6 - 3;
            A = Wbf + zr * M1v; B = Minv + zr * M1v;
            o1 = Pmat + zr * M1v; ld1 = 1024; s1 = 1.f;
            o2 = Ccat + zr * 2 * M1v;
        }
    } else {
        if (t == 0) {
            while (__hip_atomic_load(ctr, __ATOMIC_ACQUIRE,
                                     __HIP_MEMORY_SCOPE_AGENT) < 384u)
                __builtin_amdgcn_s_sleep(8);
        }
        __syncthreads();
        const int idx2 = bid - 384;
        const int zc   = idx2 >> 6;
        const int idx  = idx2 & 63;
        bx = idx & 7; by = idx >> 3;
        A = Pmat + zc * M1v; B = Wbf + zc * M1v;
        o1 = Ccat + zc * 2 * M1v + 1024; s1 = 0.01f;
    }

    const long row0 = (long)by * 128;
    const long col0 = (long)bx * 128;
    const int wr = wave >> 1, wc = wave & 1;

    // Bcat-hi copy: this block's (row0, col0) 128x128 tile of A (= Minv[z]).
    if (bhi) {
        const int rr = t >> 1, cc = (t & 1) * 64;   // 256 thr: 128 rows x 2 halves
#pragma unroll
        for (int s = 0; s < 8; s++) {
            const long src = (row0 + rr) * 1024 + col0 + cc + s * 8;
            *(bf16x8*)(bhi + (row0 + rr) * 2048 + col0 + cc + s * 8) =
                *(const bf16x8*)(A + src);
        }
    }

    f32x4 acc[4][4];
#pragma unroll
    for (int i = 0; i < 4; i++)
#pragma unroll
        for (int j = 0; j < 4; j++)
            acc[i][j] = f32x4{0.f, 0.f, 0.f, 0.f};

    const int  q  = t >> 2;
    const int  gp = ((t & 3) + 4 - ((q + (q >> 2)) & 3)) & 3;
    const bf16* gA = A + (row0 + q) * 1024 + gp * 8;
    const bf16* gB = B + (col0 + q) * 1024 + gp * 8;

    const int l15  = lane & 15;
    const int fch  = ((lane >> 4) + l15 + (l15 >> 2)) & 3;
    const int aoff = (wr * 64 + l15) * 32 + fch * 8;
    const int boff = (wc * 64 + l15) * 32 + fch * 8;

    auto stage = [&](int buf, int k0) {
        bf16* dA = sAe + buf * 4096 + wave * 512;
        bf16* dB = sBe + buf * 4096 + wave * 512;
        async_load16(gA + k0,              dA);
        async_load16(gA + 64 * 1024 + k0,  dA + 2048);
        async_load16(gB + k0,              dB);
        async_load16(gB + 64 * 1024 + k0,  dB + 2048);
    };

    stage(0, 0);
    __syncthreads();
    for (int k = 0; k < 32; k++) {
        const int cur = k & 1;
        if (k + 1 < 32) stage(cur ^ 1, (k + 1) << 5);

        bf16x8 af[4], bfv[4];
#pragma unroll
        for (int i = 0; i < 4; i++)
            af[i] = *(const bf16x8*)(sAe + cur * 4096 + aoff + i * 16 * 32);
#pragma unroll
        for (int j = 0; j < 4; j++)
            bfv[j] = *(const bf16x8*)(sBe + cur * 4096 + boff + j * 16 * 32);
#pragma unroll
        for (int i = 0; i < 4; i++)
#pragma unroll
            for (int j = 0; j < 4; j++)
                acc[i][j] = __builtin_amdgcn_mfma_f32_16x16x32_bf16(
                    af[i], bfv[j], acc[i][j], 0, 0, 0);
        __syncthreads();
    }

    float* epi = (float*)smem + wave * 1024;
    const int wbase = (lane >> 4) * 256 + (l15 >> 2) * 4 + (l15 & 3);

#pragma unroll
    for (int i = 0; i < 4; i++) {
#pragma unroll
        for (int j = 0; j < 4; j++)
#pragma unroll
            for (int r = 0; r < 4; r++)
                epi[wbase + r * 64 + 16 * j] = acc[i][j][r];

#pragma unroll
        for (int qq = 0; qq < 4; qq++) {
            const f32x4 a4 = ((const f32x4*)epi)[qq * 64 + lane];
            const long m = row0 + wr * 64 + i * 16 + qq * 4 + (lane >> 4);
            const long n = col0 + wc * 64 + 4 * l15;
            bf16x4 ov;
#pragma unroll
            for (int e = 0; e < 4; e++) ov[e] = (bf16)(s1 * a4[e]);
            *(bf16x4*)(o1 + m * (long)ld1 + n) = ov;
            if (o2) {
                bf16x4 o2v;
#pragma unroll
                for (int e = 0; e < 4; e++) o2v[e] = (bf16)(s2 * a4[e]);
                *(bf16x4*)(o2 + m * 2048 + n) = o2v;
            }
        }
    }

    if (prod) {
        __syncthreads();   // barrier implies all threads' stores drained
        if (t == 0)
            __hip_atomic_fetch_add(ctr, 1u, __ATOMIC_RELEASE,
                                   __HIP_MEMORY_SCOPE_AGENT);
    }
}

// ---------------------------------------------------------------------------
// Fused layer (R0-proven): accV = AC@Bcat^T, accU = AC@Ccat^T (K=2048) in one
// block. 128x128 tile, 4 waves, 2 blocks/CU. V never touches memory.
// ---------------------------------------------------------------------------
__global__ __launch_bounds__(256, 2)
void gemm_layer(const bf16* __restrict__ A, const bf16* __restrict__ B1,
                const bf16* __restrict__ B2, float* __restrict__ u,
                bf16* __restrict__ ACo,
                const float* __restrict__ bl, const float* __restrict__ bn)
{
    __shared__ __attribute__((aligned(16))) char smem[49152];
    bf16* sA  = (bf16*)smem;             // 2 x 4096
    bf16* sB1 = (bf16*)(smem + 16384);
    bf16* sB2 = (bf16*)(smem + 32768);

    const int t    = threadIdx.x;
    const int wave = t >> 6;
    const int lane = t & 63;
    int bx = blockIdx.x, by = blockIdx.y;
    remap_block(bx, by);
    const long row0 = (long)by * 128;
    const long col0 = (long)bx * 128;
    const int wr = wave >> 1, wc = wave & 1;

    f32x4 accU[4][4], accV[4][4];
#pragma unroll
    for (int i = 0; i < 4; i++)
#pragma unroll
        for (int j = 0; j < 4; j++) {
            accU[i][j] = f32x4{0.f, 0.f, 0.f, 0.f};
            accV[i][j] = f32x4{0.f, 0.f, 0.f, 0.f};
        }

    const int  q  = t >> 2;
    const int  gp = ((t & 3) + 4 - ((q + (q >> 2)) & 3)) & 3;
    const bf16* gA  = A  + (row0 + q) * 2048 + gp * 8;
    const bf16* gB1 = B1 + (col0 + q) * 2048 + gp * 8;
    const bf16* gB2 = B2 + (col0 + q) * 2048 + gp * 8;

    const int l15  = lane & 15;
    const int fch  = ((lane >> 4) + l15 + (l15 >> 2)) & 3;
    const int aoff = (wr * 64 + l15) * 32 + fch * 8;
    const int boff = (wc * 64 + l15) * 32 + fch * 8;

    auto stage = [&](int buf, int k0) {
        bf16* dA  = sA  + buf * 4096 + wave * 512;
        bf16* dB1 = sB1 + buf * 4096 + wave * 512;
        bf16* dB2 = sB2 + buf * 4096 + wave * 512;
        async_load16(gA  + k0,             dA);
        async_load16(gA  + 64 * 2048 + k0, dA + 2048);
        async_load16(gB1 + k0,             dB1);
        async_load16(gB1 + 64 * 2048 + k0, dB1 + 2048);
        async_load16(gB2 + k0,             dB2);
        async_load16(gB2 + 64 * 2048 + k0, dB2 + 2048);
    };

    stage(0, 0);
    __syncthreads();
    for (int k = 0; k < 64; k++) {
        const int cur = k & 1;
        if (k + 1 < 64) stage(cur ^ 1, (k + 1) << 5);

        bf16x8 af[4], b1v[4], b2v[4];
#pragma unroll
        for (int i = 0; i < 4; i++)
            af[i] = *(const bf16x8*)(sA + cur * 4096 + aoff + i * 16 * 32);
#pragma unroll
        for (int j = 0; j < 4; j++) {
            b1v[j] = *(const bf16x8*)(sB1 + cur * 4096 + boff + j * 16 * 32);
            b2v[j] = *(const bf16x8*)(sB2 + cur * 4096 + boff + j * 16 * 32);
        }
#pragma unroll
        for (int i = 0; i < 4; i++)
#pragma unroll
            for (int j = 0; j < 4; j++) {
                accV[i][j] = __builtin_amdgcn_mfma_f32_16x16x32_bf16(
                    af[i], b1v[j], accV[i][j], 0, 0, 0);
                accU[i][j] = __builtin_amdgcn_mfma_f32_16x16x32_bf16(
                    af[i], b2v[j], accU[i][j], 0, 0, 0);
            }
        __syncthreads();
    }

    float* epi = (float*)smem + wave * 1024;
    const int wbase = (lane >> 4) * 256 + (l15 >> 2) * 4 + (l15 & 3);

#pragma unroll
    for (int i = 0; i < 4; i++) {
#pragma unroll
        for (int j = 0; j < 4; j++)
#pragma unroll
            for (int r = 0; r < 4; r++)
                epi[wbase + r * 64 + 16 * j] = accV[i][j][r];
        f32x4 v4[4];
#pragma unroll
        for (int qq = 0; qq < 4; qq++)
            v4[qq] = ((const f32x4*)epi)[qq * 64 + lane];
#pragma unroll
        for (int j = 0; j < 4; j++)
#pragma unroll
            for (int r = 0; r < 4; r++)
                epi[wbase + r * 64 + 16 * j] = accU[i][j][r];

#pragma unroll
        for (int qq = 0; qq < 4; qq++) {
            const f32x4 a4 = ((const f32x4*)epi)[qq * 64 + lane];
            const long m  = row0 + wr * 64 + i * 16 + qq * 4 + (lane >> 4);
            const long n  = col0 + wc * 64 + 4 * l15;
            const long iu = m * 1024 + n;
            const f32x4 u0 = *(const f32x4*)(u + iu);
            const f32x4 c1 = *(const f32x4*)(bl + n);
            const f32x4 c2 = *(const f32x4*)(bn + n);
            f32x4 un; bf16x4 rv, hv;
#pragma unroll
            for (int e = 0; e < 4; e++) {
                un[e] = a4[e] - u0[e] - C_DT * c1[e];
                rv[e] = (bf16)(C_DTEPS * fmaxf(un[e], 0.f) - v4[qq][e]);
                hv[e] = (bf16)(un[e] + C_DT * c2[e]);
            }
            *(f32x4*)(u + iu) = un;
            *(bf16x4*)(ACo + m * 2048 + n)        = rv;
            *(bf16x4*)(ACo + m * 2048 + 1024 + n) = hv;
        }
    }
}

// logits = (Ah+Al)@(Bh+Bl)^T + bias (3-term), fp32 out, double-buffered.
__global__ __launch_bounds__(256, 2)
void gemm_split(const bf16* __restrict__ Ah, const bf16* __restrict__ Al,
                const bf16* __restrict__ Bh, const bf16* __restrict__ Bl,
                float* __restrict__ out, const float* __restrict__ bias,
                int M, int N, int K, int blim)
{
    __shared__ __attribute__((aligned(16))) char smem[65536];
    bf16* sAh = (bf16*)smem;
    bf16* sAl = (bf16*)(smem + 16384);
    bf16* sBh = (bf16*)(smem + 32768);
    bf16* sBl = (bf16*)(smem + 49152);

    const int t    = threadIdx.x;
    const int wave = t >> 6;
    const int lane = t & 63;
    int bx = blockIdx.x, by = blockIdx.y;
    remap_block(bx, by);
    const long row0 = (long)by * 128;
    const long col0 = (long)bx * 128;
    const int wr = wave >> 1, wc = wave & 1;

    f32x4 acc[4][4];
#pragma unroll
    for (int i = 0; i < 4; i++)
#pragma unroll
        for (int j = 0; j < 4; j++)
            acc[i][j] = f32x4{0.f, 0.f, 0.f, 0.f};

    const int  q  = t >> 2;
    const int  gp = ((t & 3) + 4 - ((q + (q >> 2)) & 3)) & 3;
    const long gao = (row0 + q) * (long)K + gp * 8;
    const long gbo = (col0 + q) * (long)K + gp * 8;

    const int l15  = lane & 15;
    const int fch  = ((lane >> 4) + l15 + (l15 >> 2)) & 3;
    const int aoff = (wr * 64 + l15) * 32 + fch * 8;
    const int boff = (wc * 64 + l15) * 32 + fch * 8;

    auto stage = [&](int buf, int k0) {
        const int d = buf * 4096 + wave * 512;
        async_load16(Ah + gao + k0,                 sAh + d);
        async_load16(Ah + gao + 64 * (long)K + k0,  sAh + d + 2048);
        async_load16(Al + gao + k0,                 sAl + d);
        async_load16(Al + gao + 64 * (long)K + k0,  sAl + d + 2048);
        async_load16(Bh + gbo + k0,                 sBh + d);
        async_load16(Bh + gbo + 64 * (long)K + k0,  sBh + d + 2048);
        async_load16(Bl + gbo + k0,                 sBl + d);
        async_load16(Bl + gbo + 64 * (long)K + k0,  sBl + d + 2048);
    };

    const int nIter = K >> 5;
    stage(0, 0);
    __syncthreads();
    for (int k = 0; k < nIter; k++) {
        const int cur = k & 1;
        if (k + 1 < nIter) stage(cur ^ 1, (k + 1) << 5);

        bf16x8 ah[4], al[4], bh[4], bl[4];
#pragma unroll
        for (int i = 0; i < 4; i++) {
            ah[i] = *(const bf16x8*)(sAh + cur * 4096 + aoff + i * 16 * 32);
            al[i] = *(const bf16x8*)(sAl + cur * 4096 + aoff + i * 16 * 32);
        }
#pragma unroll
        for (int j = 0; j < 4; j++) {
            bh[j] = *(const bf16x8*)(sBh + cur * 4096 + boff + j * 16 * 32);
            bl[j] = *(const bf16x8*)(sBl + cur * 4096 + boff + j * 16 * 32);
        }
#pragma unroll
        for (int i = 0; i < 4; i++)
#pragma unroll
            for (int j = 0; j < 4; j++) {
                acc[i][j] = __builtin_amdgcn_mfma_f32_16x16x32_bf16(
                    ah[i], bh[j], acc[i][j], 0, 0, 0);
                acc[i][j] = __builtin_amdgcn_mfma_f32_16x16x32_bf16(
                    ah[i], bl[j], acc[i][j], 0, 0, 0);
                acc[i][j] = __builtin_amdgcn_mfma_f32_16x16x32_bf16(
                    al[i], bh[j], acc[i][j], 0, 0, 0);
            }
        __syncthreads();
    }

    float* epi = (float*)smem + wave * 1024;
    const int wbase = (lane >> 4) * 256 + (l15 >> 2) * 4 + (l15 & 3);

#pragma unroll
    for (int i = 0; i < 4; i++) {
#pragma unroll
        for (int j = 0; j < 4; j++)
#pragma unroll
            for (int r = 0; r < 4; r++)
                epi[wbase + r * 64 + 16 * j] = acc[i][j][r];

#pragma unroll
        for (int qq = 0; qq < 4; qq++) {
            f32x4 a4 = ((const f32x4*)epi)[qq * 64 + lane];
            const long m = row0 + wr * 64 + i * 16 + qq * 4 + (lane >> 4);
            const long n = col0 + wc * 64 + 4 * l15;
            f32x4 bv = f32x4{0.f, 0.f, 0.f, 0.f};
            if (n < blim) bv = *(const f32x4*)(bias + n);
#pragma unroll
            for (int e = 0; e < 4; e++) a4[e] += bv[e];
            *(f32x4*)(out + m * (long)N + n) = a4;
        }
    }
}

// ---------------------------------------------------------------------------
// Fused prep: x conv (16384 blks) | W_in conv (2048) | W_out hi/lo (1024) |
// W1-3 bf16 + transpose (3072). One dispatch.
// ---------------------------------------------------------------------------
__global__ __launch_bounds__(256)
void prep_all(const float* __restrict__ x, bf16* __restrict__ xb,
              const float* __restrict__ win, bf16* __restrict__ winb,
              const float* __restrict__ wout, bf16* __restrict__ wouth,
              bf16* __restrict__ woutl,
              const float* __restrict__ w0, const float* __restrict__ w1,
              const float* __restrict__ w2,
              bf16* __restrict__ Wb, bf16* __restrict__ Wtb)
{
    __shared__ float tile[32][33];
    const long bid = blockIdx.x;
    const int  t   = threadIdx.x;

    if (bid < 16384) {                         // x fp32 -> bf16
        const long i4 = bid * 256 + t;
        const f32x4 v = ((const f32x4*)x)[i4];
        bf16x4 o;
#pragma unroll
        for (int e = 0; e < 4; e++) o[e] = (bf16)v[e];
        ((bf16x4*)xb)[i4] = o;
    } else if (bid < 18432) {                  // W_in fp32 -> bf16
        const long i4 = (bid - 16384) * 256 + t;
        const f32x4 v = ((const f32x4*)win)[i4];
        bf16x4 o;
#pragma unroll
        for (int e = 0; e < 4; e++) o[e] = (bf16)v[e];
        ((bf16x4*)winb)[i4] = o;
    } else if (bid < 19456) {                  // W_out -> hi/lo, pad to 1024 rows
        const long i4   = (bid - 18432) * 256 + t;
        const long base = i4 * 4;
        const int  nrow = (int)(base >> 10);
        bf16x4 h, l;
        if (nrow < 1000) {
            const f32x4 v = ((const f32x4*)wout)[i4];
#pragma unroll
            for (int e = 0; e < 4; e++) {
                bf16 hh = (bf16)v[e];
                h[e] = hh;
                l[e] = (bf16)(v[e] - (float)hh);
            }
        } else {
#pragma unroll
            for (int e = 0; e < 4; e++) { h[e] = (bf16)0.f; l[e] = (bf16)0.f; }
        }
        ((bf16x4*)wouth)[i4] = h;
        ((bf16x4*)woutl)[i4] = l;
    } else {                                   // W1-3 bf16 + transpose
        const long b2 = bid - 19456;
        const int  z  = (int)(b2 >> 10);
        const int  idx = (int)(b2 & 1023);
        const float* W = (z == 0) ? w0 : (z == 1) ? w1 : w2;
        const long zo = (long)z << 20;
        const int bxt = (idx & 31) * 32, byt = (idx >> 5) * 32;
        const int tx = t & 31, ty = t >> 5;
#pragma unroll
        for (int i = 0; i < 32; i += 8) {
            float v = W[(long)(byt + ty + i) * 1024 + bxt + tx];
            tile[ty + i][tx] = v;
            Wb[zo + (long)(byt + ty + i) * 1024 + bxt + tx] = (bf16)v;
        }
        __syncthreads();
#pragma unroll
        for (int i = 0; i < 32; i += 8)
            Wtb[zo + (long)(bxt + ty + i) * 1024 + byt + tx] = (bf16)tile[tx][ty + i];
    }
}

__global__ __launch_bounds__(256)
void softmax_rows(const float* __restrict__ logits, float* __restrict__ out)
{
    const int row = blockIdx.x;
    const float* lp = logits + (long)row * 1024;
    const int t = threadIdx.x;
    float v[4];
    float mx = -1e30f;
#pragma unroll
    for (int i = 0; i < 4; i++) {
        const int c = t + i * 256;
        v[i] = (c < 1000) ? lp[c] : -1e30f;
        mx = fmaxf(mx, v[i]);
    }
#pragma unroll
    for (int off = 32; off; off >>= 1)
        mx = fmaxf(mx, __shfl_xor(mx, off));
    __shared__ float sm[4], ss[4];
    const int wave = t >> 6;
    if ((t & 63) == 0) sm[wave] = mx;
    __syncthreads();
    mx = fmaxf(fmaxf(sm[0], sm[1]), fmaxf(sm[2], sm[3]));
    float sum = 0.f;
#pragma unroll
    for (int i = 0; i < 4; i++) {
        v[i] = __expf(v[i] - mx);
        sum += v[i];
    }
#pragma unroll
    for (int off = 32; off; off >>= 1)
        sum += __shfl_xor(sum, off);
    if ((t & 63) == 0) ss[wave] = sum;
    __syncthreads();
    const float inv = 1.f / (ss[0] + ss[1] + ss[2] + ss[3]);
#pragma unroll
    for (int i = 0; i < 4; i++) {
        const int c = t + i * 256;
        if (c < 1000) out[(long)row * 1000 + c] = v[i] * inv;
    }
}

extern "C" void kernel_launch(void* const* d_in, const int* in_sizes, int n_in,
                              void* d_out, int out_size, void* d_ws, size_t ws_size,
                              hipStream_t stream)
{
    const float* x     = (const float*)d_in[0];
    const float* W_in  = (const float*)d_in[1];
    const float* b_in  = (const float*)d_in[2];
    const float* Ws[3] = {(const float*)d_in[3], (const float*)d_in[5], (const float*)d_in[7]};
    const float* bs[3] = {(const float*)d_in[4], (const float*)d_in[6], (const float*)d_in[8]};
    const float* W_out = (const float*)d_in[9];
    const float* b_out = (const float*)d_in[10];
    float* out = (float*)d_out;

    char* ws = (char*)d_ws;
    const size_t MB = 1u << 20;
    const long M1 = 1024L * 1024;
    // Timeline: xb@0..32MB (prep -> z0m) then Bcat@18..30 written by pp2
    //   (xb dead), zh@0/zl@16 by bt<5> (Bcat dead after layers? NO - Bcat
    //   18..30 vs zh 0..16/zl 16..32: zl@16..32 overlaps Bcat@18..30! bt<5>
    //   runs AFTER the layers (Bcat dead by then) -> OK.
    // AC_b region 122..154MB transients: Wtbf@122 (prep->z0m), Minv@128
    //   (z0m->pp2), Pmat@134 (pp2 B->C), ctr@140. Dead before layer0's write.
    bf16*  xb    = (bf16*)(ws);             // 32 MB
    bf16*  zh    = (bf16*)(ws);             // 16 MB
    bf16*  zl    = (bf16*)(ws + 16 * MB);   // 16 MB
    bf16*  Bcat  = (bf16*)(ws + 18 * MB);   // 12 MB (3 x 1024x2048)
    bf16*  Winb  = (bf16*)(ws + 32 * MB);   //  4 MB
    bf16*  Wouth = (bf16*)(ws + 36 * MB);   //  2 MB
    bf16*  Woutl = (bf16*)(ws + 38 * MB);   //  2 MB
    bf16*  Wbf   = (bf16*)(ws + 40 * MB);   //  6 MB
    bf16*  Ccat  = (bf16*)(ws + 46 * MB);   // 12 MB (3 x 1024x2048)
    float* u     = (float*)(ws + 58 * MB);  // 32 MB (in-place) -> logits
    float* logits= (float*)(ws + 58 * MB);
    bf16*  AC_a  = (bf16*)(ws + 90 * MB);   // 32 MB
    bf16*  AC_b  = (bf16*)(ws + 122 * MB);  // 32 MB
    bf16*  Wtbf  = (bf16*)(ws + 122 * MB);  //  6 MB transient
    bf16*  Minv  = (bf16*)(ws + 128 * MB);  //  6 MB transient
    bf16*  Pmat  = (bf16*)(ws + 134 * MB);  //  6 MB transient
    unsigned int* ctr = (unsigned int*)(ws + 140 * MB);

    const dim3 blk(256);
    const dim3 gBig(8, 64);
    const dim3 gZ0(8, 88);

    hipMemsetAsync(ctr, 0, 64, stream);

    // 1: all conversions + transposes
    prep_all<<<22528, blk, 0, stream>>>(x, xb, W_in, Winb, W_out, Wouth, Woutl,
                                        Ws[0], Ws[1], Ws[2], Wbf, Wtbf);

    // 2: z0 (EPI0, 512 blocks) + Minv (EPI1, 192 blocks) in one dispatch
    gemm_z0m<<<gZ0, blk, 0, stream>>>(xb, Winb, Wtbf, u, AC_a, Minv,
                                      b_in, bs[0]);

    // 3: pp2 — Bcat (hi copy + lo GEMM), P, Ccat-hi [producers], then
    //    Ccat-lo [consumers] behind the in-kernel barrier.
    pp2<<<576, blk, 0, stream>>>(Minv, Wbf, Bcat, Pmat, Ccat, ctr);

    // 4-5: fused layers 0,1 (V in registers only)
    gemm_layer<<<gBig, blk, 0, stream>>>(AC_a, Bcat, Ccat, u, AC_b, bs[0], bs[1]);
    gemm_layer<<<gBig, blk, 0, stream>>>(AC_b, Bcat + 2 * M1, Ccat + 2 * M1,
                                         u, AC_a, bs[1], bs[2]);
    // 6: layer 2 u-only: z = AC_a @ Ccat2^T - u - 0.1*b3 -> zh/zl
    gemm_bt<5><<<gBig, blk, 0, stream>>>(AC_a, Ccat + 4 * M1, nullptr, zh, zl,
                                         u, bs[2], nullptr,
                                         8192, 1024, 2048, 2048, 2048,
                                         1024, 1024, 1024, 1.f, 0, 0, 0, 0);

    // 7-8: logits (3-term split) + softmax
    gemm_split<<<gBig, blk, 0, stream>>>(zh, zl, Wouth, Woutl, logits, b_out,
                                         8192, 1024, 1024, 1000);
    softmax_rows<<<8192, blk, 0, stream>>>(logits, out);
}

// Round 6
// 492.837 us; speedup vs baseline: 1.2339x; 1.2339x over previous
//
#include <hip/hip_runtime.h>
#include <hip/hip_bf16.h>
#include <cstdint>

// I/O is FP32. Derivation: c=DT=0.1, d=1+DT/EPS=11; layer out = (-u,-v):
//   V = [vr | rhsu] @ Bcat^T, Bcat = [Minv | 0.1*(Minv W^T)] (1024x2048),
//   u_raw = 0.1 V W^T = AC @ Ccat^T, Ccat = 0.1*W@Bcat = [0.1*P | 0.01*P@W^T],
//   P = W@Minv;  un = u_raw - u_in - 0.1 b;  AC_next = [10relu(un)-V | un+0.1b'],
//   Minv = (I - (0.01/11) W^T W)/11  (Neumann, trunc err ~1.5e-6).
// R12: recovery from R11's pp2 regression (agent-scope ACQUIRE in the spin
//   loop = per-poll cache invalidation storm; 174us @ 4% MfmaUtil, FETCH 4x).
//   The in-kernel barrier is replaced by a kernel boundary:
//   (a) pp2a: 384 producer blocks (Bcat-hi tile copy + Bcat-lo GEMM +
//       P/Ccat-hi GEMM), NO atomics.
//   (b) gemm_bt<2> consumer dispatch (192 blocks): Ccat-lo = 0.01*P@W^T.
//   z0m (z0 + Minv merge) kept — correct and not implicated. 9 dispatches.

typedef __bf16 bf16;
typedef __bf16 bf16x4 __attribute__((ext_vector_type(4)));
typedef __bf16 bf16x8 __attribute__((ext_vector_type(8)));
typedef float  f32x4  __attribute__((ext_vector_type(4)));

#define C_DT    0.1f
#define C_DTEPS 10.0f
#define C_DINV  (1.0f/11.0f)
#define C_MSC   (0.01f/121.0f)

__device__ __forceinline__ void async_load16(const bf16* g, bf16* l) {
    __builtin_amdgcn_global_load_lds(
        (__attribute__((address_space(1))) void*)(g),
        (__attribute__((address_space(3))) void*)(l),
        16, 0, 0);
}

// XCD-aware remap for (8,64) grids: per-XCD L2 working set ~ row-panel + B.
__device__ __forceinline__ void remap_block(int& bx, int& by) {
    if (gridDim.y == 64) {
        const int lin  = by * 8 + bx;
        const int xcd  = lin & 7;
        const int slot = lin >> 3;
        by = xcd * 8 + (slot & 7);
        bx = slot >> 3;
    }
}

// ---------------------------------------------------------------------------
// C = A @ B^T (A: MxK ld lda, B: NxK ld ldb, bf16). 128x128 tile, BK=32,
// double-buffered, batched over blockIdx.z.
// EPI 2 SCALE: out_b1 = sgn*a; if(out_b2) out_b2 = 0.1*sgn*a
// EPI 5 ULAST: un=sgn*a-e0[m*ldf+n]-0.1*e1[n]; out_b1=hi(un); out_b2=lo(un)
// ---------------------------------------------------------------------------
template<int EPI>
__global__ __launch_bounds__(256, 3)
void gemm_bt(const bf16* __restrict__ A, const bf16* __restrict__ B,
             float* __restrict__ out_f,
             bf16* __restrict__ out_b1, bf16* __restrict__ out_b2,
             const float* __restrict__ e0, const float* __restrict__ e1,
             const float* __restrict__ e2,
             int M, int N, int K, int lda, int ldb,
             int ldf, int ld1, int ld2, float sgn,
             long zsA, long zsB, long zs1, long zs2)
{
    __shared__ __attribute__((aligned(16))) char smem[32768];
    bf16* sAe = (bf16*)smem;             // 2 x 4096 elements
    bf16* sBe = (bf16*)(smem + 16384);

    const int t    = threadIdx.x;
    const int wave = t >> 6;
    const int lane = t & 63;
    int bx = blockIdx.x, by = blockIdx.y;
    remap_block(bx, by);
    const long zb = blockIdx.z;
    A += zb * zsA;
    B += zb * zsB;
    if (out_b1) out_b1 += zb * zs1;
    if (out_b2) out_b2 += zb * zs2;

    const long row0 = (long)by * 128;
    const long col0 = (long)bx * 128;
    const int wr = wave >> 1, wc = wave & 1;

    f32x4 acc[4][4];
#pragma unroll
    for (int i = 0; i < 4; i++)
#pragma unroll
        for (int j = 0; j < 4; j++)
            acc[i][j] = f32x4{0.f, 0.f, 0.f, 0.f};

    const int  q  = t >> 2;
    const int  gp = ((t & 3) + 4 - ((q + (q >> 2)) & 3)) & 3;
    const bf16* gA = A + (row0 + q) * (long)lda + gp * 8;
    const bf16* gB = B + (col0 + q) * (long)ldb + gp * 8;

    const int l15  = lane & 15;
    const int fch  = ((lane >> 4) + l15 + (l15 >> 2)) & 3;
    const int aoff = (wr * 64 + l15) * 32 + fch * 8;
    const int boff = (wc * 64 + l15) * 32 + fch * 8;

    auto stage = [&](int buf, int k0) {
        bf16* dA = sAe + buf * 4096 + wave * 512;
        bf16* dB = sBe + buf * 4096 + wave * 512;
        async_load16(gA + k0,                     dA);
        async_load16(gA + 64 * (long)lda + k0,    dA + 2048);
        async_load16(gB + k0,                     dB);
        async_load16(gB + 64 * (long)ldb + k0,    dB + 2048);
    };

    const int nIter = K >> 5;
    stage(0, 0);
    __syncthreads();
    for (int k = 0; k < nIter; k++) {
        const int cur = k & 1;
        if (k + 1 < nIter) stage(cur ^ 1, (k + 1) << 5);

        bf16x8 af[4], bfv[4];
#pragma unroll
        for (int i = 0; i < 4; i++)
            af[i] = *(const bf16x8*)(sAe + cur * 4096 + aoff + i * 16 * 32);
#pragma unroll
        for (int j = 0; j < 4; j++)
            bfv[j] = *(const bf16x8*)(sBe + cur * 4096 + boff + j * 16 * 32);
#pragma unroll
        for (int i = 0; i < 4; i++)
#pragma unroll
            for (int j = 0; j < 4; j++)
                acc[i][j] = __builtin_amdgcn_mfma_f32_16x16x32_bf16(
                    af[i], bfv[j], acc[i][j], 0, 0, 0);

        __syncthreads();
    }

    float* epi = (float*)smem + wave * 1024;
    const int wbase = (lane >> 4) * 256 + (l15 >> 2) * 4 + (l15 & 3);

#pragma unroll
    for (int i = 0; i < 4; i++) {
#pragma unroll
        for (int j = 0; j < 4; j++)
#pragma unroll
            for (int r = 0; r < 4; r++)
                epi[wbase + r * 64 + 16 * j] = acc[i][j][r];

#pragma unroll
        for (int qq = 0; qq < 4; qq++) {
            const f32x4 a4 = ((const f32x4*)epi)[qq * 64 + lane];
            const long m = row0 + wr * 64 + i * 16 + qq * 4 + (lane >> 4);
            const long n = col0 + wc * 64 + 4 * l15;

            if (EPI == 2) {
                bf16x4 ov, o2;
#pragma unroll
                for (int e = 0; e < 4; e++) {
                    ov[e] = (bf16)(sgn * a4[e]);
                    o2[e] = (bf16)(C_DT * sgn * a4[e]);
                }
                *(bf16x4*)(out_b1 + m * (long)ld1 + n) = ov;
                if (out_b2) *(bf16x4*)(out_b2 + m * (long)ld2 + n) = o2;
            } else {  // EPI 5
                const f32x4 u0 = *(const f32x4*)(e0 + m * (long)ldf + n);
                const f32x4 b1 = *(const f32x4*)(e1 + n);
                bf16x4 hv, lv;
#pragma unroll
                for (int e = 0; e < 4; e++) {
                    float un = sgn * a4[e] - u0[e] - C_DT * b1[e];
                    bf16 h = (bf16)un;
                    hv[e] = h;
                    lv[e] = (bf16)(un - (float)h);
                }
                *(bf16x4*)(out_b1 + m * (long)ld1 + n) = hv;
                *(bf16x4*)(out_b2 + m * (long)ld2 + n) = lv;
            }
        }
    }
}

// ---------------------------------------------------------------------------
// Merged z0 + Minv dispatch. Grid (8, 88):
//   by < 64 : z0 = xb@Winb^T + b_in (K=2048, M=8192, XCD-remapped):
//             u=z0 fp32; ACa=[11relu(z0) | z0+0.1*b1].
//   by >= 64: zm=(by-64)>>3: C = Wt[zm]@Wt[zm]^T (K=1024);
//             Minv[zm] = (m==n?1/11:0) - C_MSC*C  (transient @128MB; Bcat
//             aliases live xb and is filled by pp2a instead).
// ---------------------------------------------------------------------------
__global__ __launch_bounds__(256, 3)
void gemm_z0m(const bf16* __restrict__ xb, const bf16* __restrict__ winb,
              const bf16* __restrict__ wtbf,
              float* __restrict__ u, bf16* __restrict__ ACa,
              bf16* __restrict__ Minv,
              const float* __restrict__ e1, const float* __restrict__ e2)
{
    __shared__ __attribute__((aligned(16))) char smem[32768];
    bf16* sAe = (bf16*)smem;
    bf16* sBe = (bf16*)(smem + 16384);

    const int t    = threadIdx.x;
    const int wave = t >> 6;
    const int lane = t & 63;
    const long M1v = 1024L * 1024;

    const bool mainp = (blockIdx.y < 64);
    int bx, by, nIter, zm = 0;
    long lda;
    const bf16 *Abase, *Bbase;
    if (mainp) {
        const int lin  = blockIdx.y * 8 + blockIdx.x;
        const int xcd  = lin & 7;
        const int slot = lin >> 3;
        by = xcd * 8 + (slot & 7);
        bx = slot >> 3;
        lda = 2048; nIter = 64;
        Abase = xb; Bbase = winb;
    } else {
        zm = (blockIdx.y - 64) >> 3;
        by = (blockIdx.y - 64) & 7;
        bx = blockIdx.x;
        lda = 1024; nIter = 32;
        Abase = wtbf + zm * M1v; Bbase = Abase;
    }
    const long row0 = (long)by * 128;
    const long col0 = (long)bx * 128;
    const int wr = wave >> 1, wc = wave & 1;

    f32x4 acc[4][4];
#pragma unroll
    for (int i = 0; i < 4; i++)
#pragma unroll
        for (int j = 0; j < 4; j++)
            acc[i][j] = f32x4{0.f, 0.f, 0.f, 0.f};

    const int  q  = t >> 2;
    const int  gp = ((t & 3) + 4 - ((q + (q >> 2)) & 3)) & 3;
    const bf16* gA = Abase + (row0 + q) * lda + gp * 8;
    const bf16* gB = Bbase + (col0 + q) * lda + gp * 8;

    const int l15  = lane & 15;
    const int fch  = ((lane >> 4) + l15 + (l15 >> 2)) & 3;
    const int aoff = (wr * 64 + l15) * 32 + fch * 8;
    const int boff = (wc * 64 + l15) * 32 + fch * 8;

    auto stage = [&](int buf, int k0) {
        bf16* dA = sAe + buf * 4096 + wave * 512;
        bf16* dB = sBe + buf * 4096 + wave * 512;
        async_load16(gA + k0,              dA);
        async_load16(gA + 64 * lda + k0,   dA + 2048);
        async_load16(gB + k0,              dB);
        async_load16(gB + 64 * lda + k0,   dB + 2048);
    };

    stage(0, 0);
    __syncthreads();
    for (int k = 0; k < nIter; k++) {
        const int cur = k & 1;
        if (k + 1 < nIter) stage(cur ^ 1, (k + 1) << 5);

        bf16x8 af[4], bfv[4];
#pragma unroll
        for (int i = 0; i < 4; i++)
            af[i] = *(const bf16x8*)(sAe + cur * 4096 + aoff + i * 16 * 32);
#pragma unroll
        for (int j = 0; j < 4; j++)
            bfv[j] = *(const bf16x8*)(sBe + cur * 4096 + boff + j * 16 * 32);
#pragma unroll
        for (int i = 0; i < 4; i++)
#pragma unroll
            for (int j = 0; j < 4; j++)
                acc[i][j] = __builtin_amdgcn_mfma_f32_16x16x32_bf16(
                    af[i], bfv[j], acc[i][j], 0, 0, 0);
        __syncthreads();
    }

    float* epi = (float*)smem + wave * 1024;
    const int wbase = (lane >> 4) * 256 + (l15 >> 2) * 4 + (l15 & 3);

#pragma unroll
    for (int i = 0; i < 4; i++) {
#pragma unroll
        for (int j = 0; j < 4; j++)
#pragma unroll
            for (int r = 0; r < 4; r++)
                epi[wbase + r * 64 + 16 * j] = acc[i][j][r];

#pragma unroll
        for (int qq = 0; qq < 4; qq++) {
            const f32x4 a4 = ((const f32x4*)epi)[qq * 64 + lane];
            const long m = row0 + wr * 64 + i * 16 + qq * 4 + (lane >> 4);
            const long n = col0 + wc * 64 + 4 * l15;

            if (mainp) {
                const f32x4 b1 = *(const f32x4*)(e1 + n);
                const f32x4 b2 = *(const f32x4*)(e2 + n);
                f32x4 tv; bf16x4 rv, hv;
#pragma unroll
                for (int e = 0; e < 4; e++) {
                    tv[e] = a4[e] + b1[e];
                    rv[e] = (bf16)(11.f * fmaxf(tv[e], 0.f));
                    hv[e] = (bf16)(tv[e] + C_DT * b2[e]);
                }
                *(f32x4*)(u + m * 1024 + n)           = tv;
                *(bf16x4*)(ACa + m * 2048 + n)        = rv;
                *(bf16x4*)(ACa + m * 2048 + 1024 + n) = hv;
            } else {
                bf16x4 ov;
#pragma unroll
                for (int e = 0; e < 4; e++)
                    ov[e] = (bf16)(((m == n + e) ? C_DINV : 0.f) - C_MSC * a4[e]);
                *(bf16x4*)(Minv + zm * M1v + m * 1024 + n) = ov;
            }
        }
    }
}

// ---------------------------------------------------------------------------
// pp2a: producer prep GEMMs, one dispatch, 384 blocks, NO atomics.
//   z6 = bid>>6, tile idx = bid&63:
//   z6<3 : Bcat[z6][:,1024:] = 0.1*Minv[z6]@W[z6]^T; also copy its 128x128
//          Minv tile into Bcat[z6][:, :1024] (xb dead by now).
//   z6>=3: P[zr] = W[zr]@Minv[zr]^T;  Ccat[zr][:, :1024] = 0.1*P.
// Ccat-lo (needs P complete) runs in the NEXT dispatch (gemm_bt<2>).
// ---------------------------------------------------------------------------
__global__ __launch_bounds__(256, 3)
void pp2a(const bf16* __restrict__ Minv, const bf16* __restrict__ Wbf,
          bf16* __restrict__ Bcat, bf16* __restrict__ Pmat,
          bf16* __restrict__ Ccat)
{
    __shared__ __attribute__((aligned(16))) char smem[32768];
    bf16* sAe = (bf16*)smem;
    bf16* sBe = (bf16*)(smem + 16384);

    const int bid  = blockIdx.x;
    const int t    = threadIdx.x;
    const int wave = t >> 6;
    const int lane = t & 63;
    const long M1v = 1024L * 1024;

    const bf16 *A, *B;
    bf16 *o1, *o2 = nullptr;
    bf16 *bhi = nullptr;
    int ld1 = 2048;
    float s1;

    const int z6  = bid >> 6;
    const int idx = bid & 63;
    const int bx = idx & 7, by = idx >> 3;
    if (z6 < 3) {
        A = Minv + z6 * M1v; B = Wbf + z6 * M1v;
        o1 = Bcat + z6 * 2 * M1v + 1024; s1 = C_DT;
        bhi = Bcat + z6 * 2 * M1v;
    } else {
        const int zr = z6 - 3;
        A = Wbf + zr * M1v; B = Minv + zr * M1v;
        o1 = Pmat + zr * M1v; ld1 = 1024; s1 = 1.f;
        o2 = Ccat + zr * 2 * M1v;
    }

    const long row0 = (long)by * 128;
    const long col0 = (long)bx * 128;
    const int wr = wave >> 1, wc = wave & 1;

    // Bcat-hi copy: this block's (row0, col0) 128x128 tile of A (= Minv[z]).
    if (bhi) {
        const int rr = t >> 1, cc = (t & 1) * 64;
#pragma unroll
        for (int s = 0; s < 8; s++) {
            const long src = (row0 + rr) * 1024 + col0 + cc + s * 8;
            *(bf16x8*)(bhi + (row0 + rr) * 2048 + col0 + cc + s * 8) =
                *(const bf16x8*)(A + src);
        }
    }

    f32x4 acc[4][4];
#pragma unroll
    for (int i = 0; i < 4; i++)
#pragma unroll
        for (int j = 0; j < 4; j++)
            acc[i][j] = f32x4{0.f, 0.f, 0.f, 0.f};

    const int  q  = t >> 2;
    const int  gp = ((t & 3) + 4 - ((q + (q >> 2)) & 3)) & 3;
    const bf16* gA = A + (row0 + q) * 1024 + gp * 8;
    const bf16* gB = B + (col0 + q) * 1024 + gp * 8;

    const int l15  = lane & 15;
    const int fch  = ((lane >> 4) + l15 + (l15 >> 2)) & 3;
    const int aoff = (wr * 64 + l15) * 32 + fch * 8;
    const int boff = (wc * 64 + l15) * 32 + fch * 8;

    auto stage = [&](int buf, int k0) {
        bf16* dA = sAe + buf * 4096 + wave * 512;
        bf16* dB = sBe + buf * 4096 + wave * 512;
        async_load16(gA + k0,              dA);
        async_load16(gA + 64 * 1024 + k0,  dA + 2048);
        async_load16(gB + k0,              dB);
        async_load16(gB + 64 * 1024 + k0,  dB + 2048);
    };

    stage(0, 0);
    __syncthreads();
    for (int k = 0; k < 32; k++) {
        const int cur = k & 1;
        if (k + 1 < 32) stage(cur ^ 1, (k + 1) << 5);

        bf16x8 af[4], bfv[4];
#pragma unroll
        for (int i = 0; i < 4; i++)
            af[i] = *(const bf16x8*)(sAe + cur * 4096 + aoff + i * 16 * 32);
#pragma unroll
        for (int j = 0; j < 4; j++)
            bfv[j] = *(const bf16x8*)(sBe + cur * 4096 + boff + j * 16 * 32);
#pragma unroll
        for (int i = 0; i < 4; i++)
#pragma unroll
            for (int j = 0; j < 4; j++)
                acc[i][j] = __builtin_amdgcn_mfma_f32_16x16x32_bf16(
                    af[i], bfv[j], acc[i][j], 0, 0, 0);
        __syncthreads();
    }

    float* epi = (float*)smem + wave * 1024;
    const int wbase = (lane >> 4) * 256 + (l15 >> 2) * 4 + (l15 & 3);

#pragma unroll
    for (int i = 0; i < 4; i++) {
#pragma unroll
        for (int j = 0; j < 4; j++)
#pragma unroll
            for (int r = 0; r < 4; r++)
                epi[wbase + r * 64 + 16 * j] = acc[i][j][r];

#pragma unroll
        for (int qq = 0; qq < 4; qq++) {
            const f32x4 a4 = ((const f32x4*)epi)[qq * 64 + lane];
            const long m = row0 + wr * 64 + i * 16 + qq * 4 + (lane >> 4);
            const long n = col0 + wc * 64 + 4 * l15;
            bf16x4 ov;
#pragma unroll
            for (int e = 0; e < 4; e++) ov[e] = (bf16)(s1 * a4[e]);
            *(bf16x4*)(o1 + m * (long)ld1 + n) = ov;
            if (o2) {
                bf16x4 o2v;
#pragma unroll
                for (int e = 0; e < 4; e++) o2v[e] = (bf16)(C_DT * a4[e]);
                *(bf16x4*)(o2 + m * 2048 + n) = o2v;
            }
        }
    }
}

// ---------------------------------------------------------------------------
// Fused layer (R0-proven): accV = AC@Bcat^T, accU = AC@Ccat^T (K=2048) in one
// block. 128x128 tile, 4 waves, 2 blocks/CU. V never touches memory.
// ---------------------------------------------------------------------------
__global__ __launch_bounds__(256, 2)
void gemm_layer(const bf16* __restrict__ A, const bf16* __restrict__ B1,
                const bf16* __restrict__ B2, float* __restrict__ u,
                bf16* __restrict__ ACo,
                const float* __restrict__ bl, const float* __restrict__ bn)
{
    __shared__ __attribute__((aligned(16))) char smem[49152];
    bf16* sA  = (bf16*)smem;             // 2 x 4096
    bf16* sB1 = (bf16*)(smem + 16384);
    bf16* sB2 = (bf16*)(smem + 32768);

    const int t    = threadIdx.x;
    const int wave = t >> 6;
    const int lane = t & 63;
    int bx = blockIdx.x, by = blockIdx.y;
    remap_block(bx, by);
    const long row0 = (long)by * 128;
    const long col0 = (long)bx * 128;
    const int wr = wave >> 1, wc = wave & 1;

    f32x4 accU[4][4], accV[4][4];
#pragma unroll
    for (int i = 0; i < 4; i++)
#pragma unroll
        for (int j = 0; j < 4; j++) {
            accU[i][j] = f32x4{0.f, 0.f, 0.f, 0.f};
            accV[i][j] = f32x4{0.f, 0.f, 0.f, 0.f};
        }

    const int  q  = t >> 2;
    const int  gp = ((t & 3) + 4 - ((q + (q >> 2)) & 3)) & 3;
    const bf16* gA  = A  + (row0 + q) * 2048 + gp * 8;
    const bf16* gB1 = B1 + (col0 + q) * 2048 + gp * 8;
    const bf16* gB2 = B2 + (col0 + q) * 2048 + gp * 8;

    const int l15  = lane & 15;
    const int fch  = ((lane >> 4) + l15 + (l15 >> 2)) & 3;
    const int aoff = (wr * 64 + l15) * 32 + fch * 8;
    const int boff = (wc * 64 + l15) * 32 + fch * 8;

    auto stage = [&](int buf, int k0) {
        bf16* dA  = sA  + buf * 4096 + wave * 512;
        bf16* dB1 = sB1 + buf * 4096 + wave * 512;
        bf16* dB2 = sB2 + buf * 4096 + wave * 512;
        async_load16(gA  + k0,             dA);
        async_load16(gA  + 64 * 2048 + k0, dA + 2048);
        async_load16(gB1 + k0,             dB1);
        async_load16(gB1 + 64 * 2048 + k0, dB1 + 2048);
        async_load16(gB2 + k0,             dB2);
        async_load16(gB2 + 64 * 2048 + k0, dB2 + 2048);
    };

    stage(0, 0);
    __syncthreads();
    for (int k = 0; k < 64; k++) {
        const int cur = k & 1;
        if (k + 1 < 64) stage(cur ^ 1, (k + 1) << 5);

        bf16x8 af[4], b1v[4], b2v[4];
#pragma unroll
        for (int i = 0; i < 4; i++)
            af[i] = *(const bf16x8*)(sA + cur * 4096 + aoff + i * 16 * 32);
#pragma unroll
        for (int j = 0; j < 4; j++) {
            b1v[j] = *(const bf16x8*)(sB1 + cur * 4096 + boff + j * 16 * 32);
            b2v[j] = *(const bf16x8*)(sB2 + cur * 4096 + boff + j * 16 * 32);
        }
#pragma unroll
        for (int i = 0; i < 4; i++)
#pragma unroll
            for (int j = 0; j < 4; j++) {
                accV[i][j] = __builtin_amdgcn_mfma_f32_16x16x32_bf16(
                    af[i], b1v[j], accV[i][j], 0, 0, 0);
                accU[i][j] = __builtin_amdgcn_mfma_f32_16x16x32_bf16(
                    af[i], b2v[j], accU[i][j], 0, 0, 0);
            }
        __syncthreads();
    }

    float* epi = (float*)smem + wave * 1024;
    const int wbase = (lane >> 4) * 256 + (l15 >> 2) * 4 + (l15 & 3);

#pragma unroll
    for (int i = 0; i < 4; i++) {
#pragma unroll
        for (int j = 0; j < 4; j++)
#pragma unroll
            for (int r = 0; r < 4; r++)
                epi[wbase + r * 64 + 16 * j] = accV[i][j][r];
        f32x4 v4[4];
#pragma unroll
        for (int qq = 0; qq < 4; qq++)
            v4[qq] = ((const f32x4*)epi)[qq * 64 + lane];
#pragma unroll
        for (int j = 0; j < 4; j++)
#pragma unroll
            for (int r = 0; r < 4; r++)
                epi[wbase + r * 64 + 16 * j] = accU[i][j][r];

#pragma unroll
        for (int qq = 0; qq < 4; qq++) {
            const f32x4 a4 = ((const f32x4*)epi)[qq * 64 + lane];
            const long m  = row0 + wr * 64 + i * 16 + qq * 4 + (lane >> 4);
            const long n  = col0 + wc * 64 + 4 * l15;
            const long iu = m * 1024 + n;
            const f32x4 u0 = *(const f32x4*)(u + iu);
            const f32x4 c1 = *(const f32x4*)(bl + n);
            const f32x4 c2 = *(const f32x4*)(bn + n);
            f32x4 un; bf16x4 rv, hv;
#pragma unroll
            for (int e = 0; e < 4; e++) {
                un[e] = a4[e] - u0[e] - C_DT * c1[e];
                rv[e] = (bf16)(C_DTEPS * fmaxf(un[e], 0.f) - v4[qq][e]);
                hv[e] = (bf16)(un[e] + C_DT * c2[e]);
            }
            *(f32x4*)(u + iu) = un;
            *(bf16x4*)(ACo + m * 2048 + n)        = rv;
            *(bf16x4*)(ACo + m * 2048 + 1024 + n) = hv;
        }
    }
}

// logits = (Ah+Al)@(Bh+Bl)^T + bias (3-term), fp32 out, double-buffered.
__global__ __launch_bounds__(256, 2)
void gemm_split(const bf16* __restrict__ Ah, const bf16* __restrict__ Al,
                const bf16* __restrict__ Bh, const bf16* __restrict__ Bl,
                float* __restrict__ out, const float* __restrict__ bias,
                int M, int N, int K, int blim)
{
    __shared__ __attribute__((aligned(16))) char smem[65536];
    bf16* sAh = (bf16*)smem;
    bf16* sAl = (bf16*)(smem + 16384);
    bf16* sBh = (bf16*)(smem + 32768);
    bf16* sBl = (bf16*)(smem + 49152);

    const int t    = threadIdx.x;
    const int wave = t >> 6;
    const int lane = t & 63;
    int bx = blockIdx.x, by = blockIdx.y;
    remap_block(bx, by);
    const long row0 = (long)by * 128;
    const long col0 = (long)bx * 128;
    const int wr = wave >> 1, wc = wave & 1;

    f32x4 acc[4][4];
#pragma unroll
    for (int i = 0; i < 4; i++)
#pragma unroll
        for (int j = 0; j < 4; j++)
            acc[i][j] = f32x4{0.f, 0.f, 0.f, 0.f};

    const int  q  = t >> 2;
    const int  gp = ((t & 3) + 4 - ((q + (q >> 2)) & 3)) & 3;
    const long gao = (row0 + q) * (long)K + gp * 8;
    const long gbo = (col0 + q) * (long)K + gp * 8;

    const int l15  = lane & 15;
    const int fch  = ((lane >> 4) + l15 + (l15 >> 2)) & 3;
    const int aoff = (wr * 64 + l15) * 32 + fch * 8;
    const int boff = (wc * 64 + l15) * 32 + fch * 8;

    auto stage = [&](int buf, int k0) {
        const int d = buf * 4096 + wave * 512;
        async_load16(Ah + gao + k0,                 sAh + d);
        async_load16(Ah + gao + 64 * (long)K + k0,  sAh + d + 2048);
        async_load16(Al + gao + k0,                 sAl + d);
        async_load16(Al + gao + 64 * (long)K + k0,  sAl + d + 2048);
        async_load16(Bh + gbo + k0,                 sBh + d);
        async_load16(Bh + gbo + 64 * (long)K + k0,  sBh + d + 2048);
        async_load16(Bl + gbo + k0,                 sBl + d);
        async_load16(Bl + gbo + 64 * (long)K + k0,  sBl + d + 2048);
    };

    const int nIter = K >> 5;
    stage(0, 0);
    __syncthreads();
    for (int k = 0; k < nIter; k++) {
        const int cur = k & 1;
        if (k + 1 < nIter) stage(cur ^ 1, (k + 1) << 5);

        bf16x8 ah[4], al[4], bh[4], bl[4];
#pragma unroll
        for (int i = 0; i < 4; i++) {
            ah[i] = *(const bf16x8*)(sAh + cur * 4096 + aoff + i * 16 * 32);
            al[i] = *(const bf16x8*)(sAl + cur * 4096 + aoff + i * 16 * 32);
        }
#pragma unroll
        for (int j = 0; j < 4; j++) {
            bh[j] = *(const bf16x8*)(sBh + cur * 4096 + boff + j * 16 * 32);
            bl[j] = *(const bf16x8*)(sBl + cur * 4096 + boff + j * 16 * 32);
        }
#pragma unroll
        for (int i = 0; i < 4; i++)
#pragma unroll
            for (int j = 0; j < 4; j++) {
                acc[i][j] = __builtin_amdgcn_mfma_f32_16x16x32_bf16(
                    ah[i], bh[j], acc[i][j], 0, 0, 0);
                acc[i][j] = __builtin_amdgcn_mfma_f32_16x16x32_bf16(
                    ah[i], bl[j], acc[i][j], 0, 0, 0);
                acc[i][j] = __builtin_amdgcn_mfma_f32_16x16x32_bf16(
                    al[i], bh[j], acc[i][j], 0, 0, 0);
            }
        __syncthreads();
    }

    float* epi = (float*)smem + wave * 1024;
    const int wbase = (lane >> 4) * 256 + (l15 >> 2) * 4 + (l15 & 3);

#pragma unroll
    for (int i = 0; i < 4; i++) {
#pragma unroll
        for (int j = 0; j < 4; j++)
#pragma unroll
            for (int r = 0; r < 4; r++)
                epi[wbase + r * 64 + 16 * j] = acc[i][j][r];

#pragma unroll
        for (int qq = 0; qq < 4; qq++) {
            f32x4 a4 = ((const f32x4*)epi)[qq * 64 + lane];
            const long m = row0 + wr * 64 + i * 16 + qq * 4 + (lane >> 4);
            const long n = col0 + wc * 64 + 4 * l15;
            f32x4 bv = f32x4{0.f, 0.f, 0.f, 0.f};
            if (n < blim) bv = *(const f32x4*)(bias + n);
#pragma unroll
            for (int e = 0; e < 4; e++) a4[e] += bv[e];
            *(f32x4*)(out + m * (long)N + n) = a4;
        }
    }
}

// ---------------------------------------------------------------------------
// Fused prep: x conv (16384 blks) | W_in conv (2048) | W_out hi/lo (1024) |
// W1-3 bf16 + transpose (3072). One dispatch.
// ---------------------------------------------------------------------------
__global__ __launch_bounds__(256)
void prep_all(const float* __restrict__ x, bf16* __restrict__ xb,
              const float* __restrict__ win, bf16* __restrict__ winb,
              const float* __restrict__ wout, bf16* __restrict__ wouth,
              bf16* __restrict__ woutl,
              const float* __restrict__ w0, const float* __restrict__ w1,
              const float* __restrict__ w2,
              bf16* __restrict__ Wb, bf16* __restrict__ Wtb)
{
    __shared__ float tile[32][33];
    const long bid = blockIdx.x;
    const int  t   = threadIdx.x;

    if (bid < 16384) {                         // x fp32 -> bf16
        const long i4 = bid * 256 + t;
        const f32x4 v = ((const f32x4*)x)[i4];
        bf16x4 o;
#pragma unroll
        for (int e = 0; e < 4; e++) o[e] = (bf16)v[e];
        ((bf16x4*)xb)[i4] = o;
    } else if (bid < 18432) {                  // W_in fp32 -> bf16
        const long i4 = (bid - 16384) * 256 + t;
        const f32x4 v = ((const f32x4*)win)[i4];
        bf16x4 o;
#pragma unroll
        for (int e = 0; e < 4; e++) o[e] = (bf16)v[e];
        ((bf16x4*)winb)[i4] = o;
    } else if (bid < 19456) {                  // W_out -> hi/lo, pad to 1024 rows
        const long i4   = (bid - 18432) * 256 + t;
        const long base = i4 * 4;
        const int  nrow = (int)(base >> 10);
        bf16x4 h, l;
        if (nrow < 1000) {
            const f32x4 v = ((const f32x4*)wout)[i4];
#pragma unroll
            for (int e = 0; e < 4; e++) {
                bf16 hh = (bf16)v[e];
                h[e] = hh;
                l[e] = (bf16)(v[e] - (float)hh);
            }
        } else {
#pragma unroll
            for (int e = 0; e < 4; e++) { h[e] = (bf16)0.f; l[e] = (bf16)0.f; }
        }
        ((bf16x4*)wouth)[i4] = h;
        ((bf16x4*)woutl)[i4] = l;
    } else {                                   // W1-3 bf16 + transpose
        const long b2 = bid - 19456;
        const int  z  = (int)(b2 >> 10);
        const int  idx = (int)(b2 & 1023);
        const float* W = (z == 0) ? w0 : (z == 1) ? w1 : w2;
        const long zo = (long)z << 20;
        const int bxt = (idx & 31) * 32, byt = (idx >> 5) * 32;
        const int tx = t & 31, ty = t >> 5;
#pragma unroll
        for (int i = 0; i < 32; i += 8) {
            float v = W[(long)(byt + ty + i) * 1024 + bxt + tx];
            tile[ty + i][tx] = v;
            Wb[zo + (long)(byt + ty + i) * 1024 + bxt + tx] = (bf16)v;
        }
        __syncthreads();
#pragma unroll
        for (int i = 0; i < 32; i += 8)
            Wtb[zo + (long)(bxt + ty + i) * 1024 + byt + tx] = (bf16)tile[tx][ty + i];
    }
}

__global__ __launch_bounds__(256)
void softmax_rows(const float* __restrict__ logits, float* __restrict__ out)
{
    const int row = blockIdx.x;
    const float* lp = logits + (long)row * 1024;
    const int t = threadIdx.x;
    float v[4];
    float mx = -1e30f;
#pragma unroll
    for (int i = 0; i < 4; i++) {
        const int c = t + i * 256;
        v[i] = (c < 1000) ? lp[c] : -1e30f;
        mx = fmaxf(mx, v[i]);
    }
#pragma unroll
    for (int off = 32; off; off >>= 1)
        mx = fmaxf(mx, __shfl_xor(mx, off));
    __shared__ float sm[4], ss[4];
    const int wave = t >> 6;
    if ((t & 63) == 0) sm[wave] = mx;
    __syncthreads();
    mx = fmaxf(fmaxf(sm[0], sm[1]), fmaxf(sm[2], sm[3]));
    float sum = 0.f;
#pragma unroll
    for (int i = 0; i < 4; i++) {
        v[i] = __expf(v[i] - mx);
        sum += v[i];
    }
#pragma unroll
    for (int off = 32; off; off >>= 1)
        sum += __shfl_xor(sum, off);
    if ((t & 63) == 0) ss[wave] = sum;
    __syncthreads();
    const float inv = 1.f / (ss[0] + ss[1] + ss[2] + ss[3]);
#pragma unroll
    for (int i = 0; i < 4; i++) {
        const int c = t + i * 256;
        if (c < 1000) out[(long)row * 1000 + c] = v[i] * inv;
    }
}

extern "C" void kernel_launch(void* const* d_in, const int* in_sizes, int n_in,
                              void* d_out, int out_size, void* d_ws, size_t ws_size,
                              hipStream_t stream)
{
    const float* x     = (const float*)d_in[0];
    const float* W_in  = (const float*)d_in[1];
    const float* b_in  = (const float*)d_in[2];
    const float* Ws[3] = {(const float*)d_in[3], (const float*)d_in[5], (const float*)d_in[7]};
    const float* bs[3] = {(const float*)d_in[4], (const float*)d_in[6], (const float*)d_in[8]};
    const float* W_out = (const float*)d_in[9];
    const float* b_out = (const float*)d_in[10];
    float* out = (float*)d_out;

    char* ws = (char*)d_ws;
    const size_t MB = 1u << 20;
    const long M1 = 1024L * 1024;
    // Timeline: xb@0..32MB (prep -> z0m); Bcat@18..30 written by pp2a (xb
    //   dead); zh@0/zl@16 by bt<5> (after layers; Bcat dead by then).
    // AC_b region 122..154MB transients: Wtbf@122 (prep->z0m), Minv@128
    //   (z0m->pp2a), Pmat@134 (pp2a->bt<2>). All dead before layer0's write.
    bf16*  xb    = (bf16*)(ws);             // 32 MB
    bf16*  zh    = (bf16*)(ws);             // 16 MB
    bf16*  zl    = (bf16*)(ws + 16 * MB);   // 16 MB
    bf16*  Bcat  = (bf16*)(ws + 18 * MB);   // 12 MB (3 x 1024x2048)
    bf16*  Winb  = (bf16*)(ws + 32 * MB);   //  4 MB
    bf16*  Wouth = (bf16*)(ws + 36 * MB);   //  2 MB
    bf16*  Woutl = (bf16*)(ws + 38 * MB);   //  2 MB
    bf16*  Wbf   = (bf16*)(ws + 40 * MB);   //  6 MB
    bf16*  Ccat  = (bf16*)(ws + 46 * MB);   // 12 MB (3 x 1024x2048)
    float* u     = (float*)(ws + 58 * MB);  // 32 MB (in-place) -> logits
    float* logits= (float*)(ws + 58 * MB);
    bf16*  AC_a  = (bf16*)(ws + 90 * MB);   // 32 MB
    bf16*  AC_b  = (bf16*)(ws + 122 * MB);  // 32 MB
    bf16*  Wtbf  = (bf16*)(ws + 122 * MB);  //  6 MB transient
    bf16*  Minv  = (bf16*)(ws + 128 * MB);  //  6 MB transient
    bf16*  Pmat  = (bf16*)(ws + 134 * MB);  //  6 MB transient

    const dim3 blk(256);
    const dim3 gBig(8, 64);
    const dim3 gZ0(8, 88);
    const dim3 gSm3(8, 8, 3);

    // 1: all conversions + transposes
    prep_all<<<22528, blk, 0, stream>>>(x, xb, W_in, Winb, W_out, Wouth, Woutl,
                                        Ws[0], Ws[1], Ws[2], Wbf, Wtbf);

    // 2: z0 (EPI0, 512 blocks) + Minv (EPI1, 192 blocks) in one dispatch
    gemm_z0m<<<gZ0, blk, 0, stream>>>(xb, Winb, Wtbf, u, AC_a, Minv,
                                      b_in, bs[0]);

    // 3: pp2a — Bcat (hi copy + lo GEMM), P, Ccat-hi. No atomics.
    pp2a<<<384, blk, 0, stream>>>(Minv, Wbf, Bcat, Pmat, Ccat);

    // 4: Ccat[:,1024:] = 0.01 * P @ W^T (consumer of P, own dispatch)
    gemm_bt<2><<<gSm3, blk, 0, stream>>>(Pmat, Wbf, nullptr, Ccat + 1024, nullptr,
                                         nullptr, nullptr, nullptr,
                                         1024, 1024, 1024, 1024, 1024,
                                         0, 2048, 0, 0.01f, M1, M1, 2 * M1, 0);

    // 5-6: fused layers 0,1 (V in registers only)
    gemm_layer<<<gBig, blk, 0, stream>>>(AC_a, Bcat, Ccat, u, AC_b, bs[0], bs[1]);
    gemm_layer<<<gBig, blk, 0, stream>>>(AC_b, Bcat + 2 * M1, Ccat + 2 * M1,
                                         u, AC_a, bs[1], bs[2]);
    // 7: layer 2 u-only: z = AC_a @ Ccat2^T - u - 0.1*b3 -> zh/zl
    gemm_bt<5><<<gBig, blk, 0, stream>>>(AC_a, Ccat + 4 * M1, nullptr, zh, zl,
                                         u, bs[2], nullptr,
                                         8192, 1024, 2048, 2048, 2048,
                                         1024, 1024, 1024, 1.f, 0, 0, 0, 0);

    // 8-9: logits (3-term split) + softmax
    gemm_split<<<gBig, blk, 0, stream>>>(zh, zl, Wouth, Woutl, logits, b_out,
                                         8192, 1024, 1024, 1000);
    softmax_rows<<<8192, blk, 0, stream>>>(logits, out);
}

// Round 7
// 478.767 us; speedup vs baseline: 1.2701x; 1.0294x over previous
//
#include <hip/hip_runtime.h>
#include <hip/hip_bf16.h>
#include <cstdint>

// I/O is FP32. Derivation: c=DT=0.1, d=1+DT/EPS=11; layer out = (-u,-v):
//   V = [vr | rhsu] @ Bcat^T, Bcat = [Minv | 0.1*(Minv W^T)] (1024x2048),
//   u_raw = 0.1 V W^T = AC @ Ccat^T, Ccat = [0.1*W@Minv | 0.01*(W@Minv)@W^T],
//   un = u_raw - u_in - 0.1 b;  AC_next = [10relu(un)-V | un+0.1b'],
//   Minv = I/11 - C_MSC*(W^T W)  (Neumann, trunc err ~1.5e-6).
// R13: prep-DAG shortening on top of R12 (492.8us best):
//   (a) Ccat-lo without P: with G = W@W^T,
//       Ccat-lo = (0.01/11)*G - (1e-4/121)*(G@G)  [G symmetric -> A=B=G].
//       G joins z0m's tail (3 GEMMs); G@G joins pp2b. bt<2> dispatch and
//       Pmat buffer eliminated.
//   (b) dead Bcat[2] work dropped (layers only read Bcat[0..1]).
//   (c) pp2b: 512 independent blocks (128 Bcat lo+hi, 192 Ccat-hi =
//       0.1*W@Minv, 192 Ccat-lo = G@G epi). Dispatches 9 -> 8.

typedef __bf16 bf16;
typedef __bf16 bf16x4 __attribute__((ext_vector_type(4)));
typedef __bf16 bf16x8 __attribute__((ext_vector_type(8)));
typedef float  f32x4  __attribute__((ext_vector_type(4)));

#define C_DT    0.1f
#define C_DTEPS 10.0f
#define C_DINV  (1.0f/11.0f)
#define C_MSC   (0.01f/121.0f)
#define SC_G1   (0.01f/11.0f)      // 0.01*C_DINV
#define SC_G2   (0.0001f/121.0f)   // 0.01*C_MSC

__device__ __forceinline__ void async_load16(const bf16* g, bf16* l) {
    __builtin_amdgcn_global_load_lds(
        (__attribute__((address_space(1))) void*)(g),
        (__attribute__((address_space(3))) void*)(l),
        16, 0, 0);
}

// XCD-aware remap for (8,64) grids: per-XCD L2 working set ~ row-panel + B.
__device__ __forceinline__ void remap_block(int& bx, int& by) {
    if (gridDim.y == 64) {
        const int lin  = by * 8 + bx;
        const int xcd  = lin & 7;
        const int slot = lin >> 3;
        by = xcd * 8 + (slot & 7);
        bx = slot >> 3;
    }
}

// ---------------------------------------------------------------------------
// C = A @ B^T (A: MxK ld lda, B: NxK ld ldb, bf16). 128x128 tile, BK=32,
// double-buffered.
// EPI 5 ULAST: un=sgn*a-e0[m*ldf+n]-0.1*e1[n]; out_b1=hi(un); out_b2=lo(un)
// ---------------------------------------------------------------------------
template<int EPI>
__global__ __launch_bounds__(256, 3)
void gemm_bt(const bf16* __restrict__ A, const bf16* __restrict__ B,
             float* __restrict__ out_f,
             bf16* __restrict__ out_b1, bf16* __restrict__ out_b2,
             const float* __restrict__ e0, const float* __restrict__ e1,
             const float* __restrict__ e2,
             int M, int N, int K, int lda, int ldb,
             int ldf, int ld1, int ld2, float sgn,
             long zsA, long zsB, long zs1, long zs2)
{
    __shared__ __attribute__((aligned(16))) char smem[32768];
    bf16* sAe = (bf16*)smem;             // 2 x 4096 elements
    bf16* sBe = (bf16*)(smem + 16384);

    const int t    = threadIdx.x;
    const int wave = t >> 6;
    const int lane = t & 63;
    int bx = blockIdx.x, by = blockIdx.y;
    remap_block(bx, by);
    const long zb = blockIdx.z;
    A += zb * zsA;
    B += zb * zsB;
    if (out_b1) out_b1 += zb * zs1;
    if (out_b2) out_b2 += zb * zs2;

    const long row0 = (long)by * 128;
    const long col0 = (long)bx * 128;
    const int wr = wave >> 1, wc = wave & 1;

    f32x4 acc[4][4];
#pragma unroll
    for (int i = 0; i < 4; i++)
#pragma unroll
        for (int j = 0; j < 4; j++)
            acc[i][j] = f32x4{0.f, 0.f, 0.f, 0.f};

    const int  q  = t >> 2;
    const int  gp = ((t & 3) + 4 - ((q + (q >> 2)) & 3)) & 3;
    const bf16* gA = A + (row0 + q) * (long)lda + gp * 8;
    const bf16* gB = B + (col0 + q) * (long)ldb + gp * 8;

    const int l15  = lane & 15;
    const int fch  = ((lane >> 4) + l15 + (l15 >> 2)) & 3;
    const int aoff = (wr * 64 + l15) * 32 + fch * 8;
    const int boff = (wc * 64 + l15) * 32 + fch * 8;

    auto stage = [&](int buf, int k0) {
        bf16* dA = sAe + buf * 4096 + wave * 512;
        bf16* dB = sBe + buf * 4096 + wave * 512;
        async_load16(gA + k0,                     dA);
        async_load16(gA + 64 * (long)lda + k0,    dA + 2048);
        async_load16(gB + k0,                     dB);
        async_load16(gB + 64 * (long)ldb + k0,    dB + 2048);
    };

    const int nIter = K >> 5;
    stage(0, 0);
    __syncthreads();
    for (int k = 0; k < nIter; k++) {
        const int cur = k & 1;
        if (k + 1 < nIter) stage(cur ^ 1, (k + 1) << 5);

        bf16x8 af[4], bfv[4];
#pragma unroll
        for (int i = 0; i < 4; i++)
            af[i] = *(const bf16x8*)(sAe + cur * 4096 + aoff + i * 16 * 32);
#pragma unroll
        for (int j = 0; j < 4; j++)
            bfv[j] = *(const bf16x8*)(sBe + cur * 4096 + boff + j * 16 * 32);
#pragma unroll
        for (int i = 0; i < 4; i++)
#pragma unroll
            for (int j = 0; j < 4; j++)
                acc[i][j] = __builtin_amdgcn_mfma_f32_16x16x32_bf16(
                    af[i], bfv[j], acc[i][j], 0, 0, 0);

        __syncthreads();
    }

    float* epi = (float*)smem + wave * 1024;
    const int wbase = (lane >> 4) * 256 + (l15 >> 2) * 4 + (l15 & 3);

#pragma unroll
    for (int i = 0; i < 4; i++) {
#pragma unroll
        for (int j = 0; j < 4; j++)
#pragma unroll
            for (int r = 0; r < 4; r++)
                epi[wbase + r * 64 + 16 * j] = acc[i][j][r];

#pragma unroll
        for (int qq = 0; qq < 4; qq++) {
            const f32x4 a4 = ((const f32x4*)epi)[qq * 64 + lane];
            const long m = row0 + wr * 64 + i * 16 + qq * 4 + (lane >> 4);
            const long n = col0 + wc * 64 + 4 * l15;

            if (EPI == 5) {
                const f32x4 u0 = *(const f32x4*)(e0 + m * (long)ldf + n);
                const f32x4 b1 = *(const f32x4*)(e1 + n);
                bf16x4 hv, lv;
#pragma unroll
                for (int e = 0; e < 4; e++) {
                    float un = sgn * a4[e] - u0[e] - C_DT * b1[e];
                    bf16 h = (bf16)un;
                    hv[e] = h;
                    lv[e] = (bf16)(un - (float)h);
                }
                *(bf16x4*)(out_b1 + m * (long)ld1 + n) = hv;
                *(bf16x4*)(out_b2 + m * (long)ld2 + n) = lv;
            }
        }
    }
}

// ---------------------------------------------------------------------------
// Merged z0 + Minv + G dispatch. Grid (8, 112):
//   by < 64  : z0 = xb@Winb^T + b_in (K=2048, M=8192, XCD-remapped):
//              u=z0 fp32; ACa=[11relu(z0) | z0+0.1*b1].
//   64<=by<88: zm=(by-64)>>3: H = Wt[zm]@Wt[zm]^T (K=1024);
//              Minv[zm] = (m==n?1/11:0) - C_MSC*H  (transient @128MB).
//   by >= 88 : zm=(by-88)>>3: G[zm] = W[zm]@W[zm]^T (K=1024), bf16 store
//              (transient @134MB).
// ---------------------------------------------------------------------------
__global__ __launch_bounds__(256, 3)
void gemm_z0m(const bf16* __restrict__ xb, const bf16* __restrict__ winb,
              const bf16* __restrict__ wtbf, const bf16* __restrict__ wbf,
              float* __restrict__ u, bf16* __restrict__ ACa,
              bf16* __restrict__ Minv, bf16* __restrict__ Gmat,
              const float* __restrict__ e1, const float* __restrict__ e2)
{
    __shared__ __attribute__((aligned(16))) char smem[32768];
    bf16* sAe = (bf16*)smem;
    bf16* sBe = (bf16*)(smem + 16384);

    const int t    = threadIdx.x;
    const int wave = t >> 6;
    const int lane = t & 63;
    const long M1v = 1024L * 1024;

    const bool mainp = (blockIdx.y < 64);
    bool isG = false;
    int bx, by, nIter, zm = 0;
    long lda;
    const bf16 *Abase, *Bbase;
    if (mainp) {
        const int lin  = blockIdx.y * 8 + blockIdx.x;
        const int xcd  = lin & 7;
        const int slot = lin >> 3;
        by = xcd * 8 + (slot & 7);
        bx = slot >> 3;
        lda = 2048; nIter = 64;
        Abase = xb; Bbase = winb;
    } else {
        const int ty = blockIdx.y - 64;          // 0..47
        isG = (ty >= 24);
        zm = (isG ? ty - 24 : ty) >> 3;
        by = ty & 7;
        bx = blockIdx.x;
        lda = 1024; nIter = 32;
        Abase = (isG ? wbf : wtbf) + zm * M1v; Bbase = Abase;
    }
    const long row0 = (long)by * 128;
    const long col0 = (long)bx * 128;
    const int wr = wave >> 1, wc = wave & 1;

    f32x4 acc[4][4];
#pragma unroll
    for (int i = 0; i < 4; i++)
#pragma unroll
        for (int j = 0; j < 4; j++)
            acc[i][j] = f32x4{0.f, 0.f, 0.f, 0.f};

    const int  q  = t >> 2;
    const int  gp = ((t & 3) + 4 - ((q + (q >> 2)) & 3)) & 3;
    const bf16* gA = Abase + (row0 + q) * lda + gp * 8;
    const bf16* gB = Bbase + (col0 + q) * lda + gp * 8;

    const int l15  = lane & 15;
    const int fch  = ((lane >> 4) + l15 + (l15 >> 2)) & 3;
    const int aoff = (wr * 64 + l15) * 32 + fch * 8;
    const int boff = (wc * 64 + l15) * 32 + fch * 8;

    auto stage = [&](int buf, int k0) {
        bf16* dA = sAe + buf * 4096 + wave * 512;
        bf16* dB = sBe + buf * 4096 + wave * 512;
        async_load16(gA + k0,              dA);
        async_load16(gA + 64 * lda + k0,   dA + 2048);
        async_load16(gB + k0,              dB);
        async_load16(gB + 64 * lda + k0,   dB + 2048);
    };

    stage(0, 0);
    __syncthreads();
    for (int k = 0; k < nIter; k++) {
        const int cur = k & 1;
        if (k + 1 < nIter) stage(cur ^ 1, (k + 1) << 5);

        bf16x8 af[4], bfv[4];
#pragma unroll
        for (int i = 0; i < 4; i++)
            af[i] = *(const bf16x8*)(sAe + cur * 4096 + aoff + i * 16 * 32);
#pragma unroll
        for (int j = 0; j < 4; j++)
            bfv[j] = *(const bf16x8*)(sBe + cur * 4096 + boff + j * 16 * 32);
#pragma unroll
        for (int i = 0; i < 4; i++)
#pragma unroll
            for (int j = 0; j < 4; j++)
                acc[i][j] = __builtin_amdgcn_mfma_f32_16x16x32_bf16(
                    af[i], bfv[j], acc[i][j], 0, 0, 0);
        __syncthreads();
    }

    float* epi = (float*)smem + wave * 1024;
    const int wbase = (lane >> 4) * 256 + (l15 >> 2) * 4 + (l15 & 3);

#pragma unroll
    for (int i = 0; i < 4; i++) {
#pragma unroll
        for (int j = 0; j < 4; j++)
#pragma unroll
            for (int r = 0; r < 4; r++)
                epi[wbase + r * 64 + 16 * j] = acc[i][j][r];

#pragma unroll
        for (int qq = 0; qq < 4; qq++) {
            const f32x4 a4 = ((const f32x4*)epi)[qq * 64 + lane];
            const long m = row0 + wr * 64 + i * 16 + qq * 4 + (lane >> 4);
            const long n = col0 + wc * 64 + 4 * l15;

            if (mainp) {
                const f32x4 b1 = *(const f32x4*)(e1 + n);
                const f32x4 b2 = *(const f32x4*)(e2 + n);
                f32x4 tv; bf16x4 rv, hv;
#pragma unroll
                for (int e = 0; e < 4; e++) {
                    tv[e] = a4[e] + b1[e];
                    rv[e] = (bf16)(11.f * fmaxf(tv[e], 0.f));
                    hv[e] = (bf16)(tv[e] + C_DT * b2[e]);
                }
                *(f32x4*)(u + m * 1024 + n)           = tv;
                *(bf16x4*)(ACa + m * 2048 + n)        = rv;
                *(bf16x4*)(ACa + m * 2048 + 1024 + n) = hv;
            } else if (isG) {
                bf16x4 ov;
#pragma unroll
                for (int e = 0; e < 4; e++) ov[e] = (bf16)a4[e];
                *(bf16x4*)(Gmat + zm * M1v + m * 1024 + n) = ov;
            } else {
                bf16x4 ov;
#pragma unroll
                for (int e = 0; e < 4; e++)
                    ov[e] = (bf16)(((m == n + e) ? C_DINV : 0.f) - C_MSC * a4[e]);
                *(bf16x4*)(Minv + zm * M1v + m * 1024 + n) = ov;
            }
        }
    }
}

// ---------------------------------------------------------------------------
// pp2b: all level-1 prep GEMMs, one dispatch, 512 independent blocks
// (32KB LDS + (256,3) -> all co-resident; inputs Minv/G/W all from z0m).
//   bid <  128 (role 0): z=bid>>6 in {0,1}:
//     Bcat[z][:,1024:] = 0.1*Minv[z]@W[z]^T; copy its 128x128 Minv tile
//     into Bcat[z][:, :1024] (xb dead by now).
//   128<=bid<320 (role 1): z=(bid-128)>>6 in {0,1,2}:
//     Ccat[z][:, :1024] = 0.1*W[z]@Minv[z]   (Minv symmetric).
//   bid >= 320 (role 2): z=(bid-320)>>6 in {0,1,2}:
//     Ccat[z][:,1024:] = SC_G1*G[z] - SC_G2*(G[z]@G[z])  (G symmetric).
// ---------------------------------------------------------------------------
__global__ __launch_bounds__(256, 3)
void pp2b(const bf16* __restrict__ Minv, const bf16* __restrict__ Wbf,
          const bf16* __restrict__ Gmat,
          bf16* __restrict__ Bcat, bf16* __restrict__ Ccat)
{
    __shared__ __attribute__((aligned(16))) char smem[32768];
    bf16* sAe = (bf16*)smem;
    bf16* sBe = (bf16*)(smem + 16384);

    const int bid  = blockIdx.x;
    const int t    = threadIdx.x;
    const int wave = t >> 6;
    const int lane = t & 63;
    const long M1v = 1024L * 1024;

    int role, z, idx;
    if (bid < 128)      { role = 0; z = bid >> 6;          idx = bid & 63; }
    else if (bid < 320) { role = 1; z = (bid - 128) >> 6;  idx = (bid - 128) & 63; }
    else                { role = 2; z = (bid - 320) >> 6;  idx = (bid - 320) & 63; }
    const int bx = idx & 7, by = idx >> 3;

    const bf16 *A, *B;
    bf16 *o1;
    bf16 *bhi = nullptr;
    const bf16* Gsrc = nullptr;
    if (role == 0) {
        A = Minv + z * M1v; B = Wbf + z * M1v;
        o1 = Bcat + z * 2 * M1v + 1024;
        bhi = Bcat + z * 2 * M1v;
    } else if (role == 1) {
        A = Wbf + z * M1v; B = Minv + z * M1v;
        o1 = Ccat + z * 2 * M1v;
    } else {
        A = Gmat + z * M1v; B = A;
        o1 = Ccat + z * 2 * M1v + 1024;
        Gsrc = A;
    }

    const long row0 = (long)by * 128;
    const long col0 = (long)bx * 128;
    const int wr = wave >> 1, wc = wave & 1;

    // Bcat-hi copy: this block's (row0, col0) 128x128 tile of A (= Minv[z]).
    if (bhi) {
        const int rr = t >> 1, cc = (t & 1) * 64;
#pragma unroll
        for (int s = 0; s < 8; s++) {
            const long src = (row0 + rr) * 1024 + col0 + cc + s * 8;
            *(bf16x8*)(bhi + (row0 + rr) * 2048 + col0 + cc + s * 8) =
                *(const bf16x8*)(A + src);
        }
    }

    f32x4 acc[4][4];
#pragma unroll
    for (int i = 0; i < 4; i++)
#pragma unroll
        for (int j = 0; j < 4; j++)
            acc[i][j] = f32x4{0.f, 0.f, 0.f, 0.f};

    const int  q  = t >> 2;
    const int  gp = ((t & 3) + 4 - ((q + (q >> 2)) & 3)) & 3;
    const bf16* gA = A + (row0 + q) * 1024 + gp * 8;
    const bf16* gB = B + (col0 + q) * 1024 + gp * 8;

    const int l15  = lane & 15;
    const int fch  = ((lane >> 4) + l15 + (l15 >> 2)) & 3;
    const int aoff = (wr * 64 + l15) * 32 + fch * 8;
    const int boff = (wc * 64 + l15) * 32 + fch * 8;

    auto stage = [&](int buf, int k0) {
        bf16* dA = sAe + buf * 4096 + wave * 512;
        bf16* dB = sBe + buf * 4096 + wave * 512;
        async_load16(gA + k0,              dA);
        async_load16(gA + 64 * 1024 + k0,  dA + 2048);
        async_load16(gB + k0,              dB);
        async_load16(gB + 64 * 1024 + k0,  dB + 2048);
    };

    stage(0, 0);
    __syncthreads();
    for (int k = 0; k < 32; k++) {
        const int cur = k & 1;
        if (k + 1 < 32) stage(cur ^ 1, (k + 1) << 5);

        bf16x8 af[4], bfv[4];
#pragma unroll
        for (int i = 0; i < 4; i++)
            af[i] = *(const bf16x8*)(sAe + cur * 4096 + aoff + i * 16 * 32);
#pragma unroll
        for (int j = 0; j < 4; j++)
            bfv[j] = *(const bf16x8*)(sBe + cur * 4096 + boff + j * 16 * 32);
#pragma unroll
        for (int i = 0; i < 4; i++)
#pragma unroll
            for (int j = 0; j < 4; j++)
                acc[i][j] = __builtin_amdgcn_mfma_f32_16x16x32_bf16(
                    af[i], bfv[j], acc[i][j], 0, 0, 0);
        __syncthreads();
    }

    float* epi = (float*)smem + wave * 1024;
    const int wbase = (lane >> 4) * 256 + (l15 >> 2) * 4 + (l15 & 3);

#pragma unroll
    for (int i = 0; i < 4; i++) {
#pragma unroll
        for (int j = 0; j < 4; j++)
#pragma unroll
            for (int r = 0; r < 4; r++)
                epi[wbase + r * 64 + 16 * j] = acc[i][j][r];

#pragma unroll
        for (int qq = 0; qq < 4; qq++) {
            const f32x4 a4 = ((const f32x4*)epi)[qq * 64 + lane];
            const long m = row0 + wr * 64 + i * 16 + qq * 4 + (lane >> 4);
            const long n = col0 + wc * 64 + 4 * l15;
            bf16x4 ov;
            if (role == 2) {
                const bf16x4 g4 = *(const bf16x4*)(Gsrc + m * 1024 + n);
#pragma unroll
                for (int e = 0; e < 4; e++)
                    ov[e] = (bf16)(SC_G1 * (float)g4[e] - SC_G2 * a4[e]);
            } else {
#pragma unroll
                for (int e = 0; e < 4; e++) ov[e] = (bf16)(C_DT * a4[e]);
            }
            *(bf16x4*)(o1 + m * 2048 + n) = ov;
        }
    }
}

// ---------------------------------------------------------------------------
// Fused layer (R0-proven): accV = AC@Bcat^T, accU = AC@Ccat^T (K=2048) in one
// block. 128x128 tile, 4 waves, 2 blocks/CU. V never touches memory.
// ---------------------------------------------------------------------------
__global__ __launch_bounds__(256, 2)
void gemm_layer(const bf16* __restrict__ A, const bf16* __restrict__ B1,
                const bf16* __restrict__ B2, float* __restrict__ u,
                bf16* __restrict__ ACo,
                const float* __restrict__ bl, const float* __restrict__ bn)
{
    __shared__ __attribute__((aligned(16))) char smem[49152];
    bf16* sA  = (bf16*)smem;             // 2 x 4096
    bf16* sB1 = (bf16*)(smem + 16384);
    bf16* sB2 = (bf16*)(smem + 32768);

    const int t    = threadIdx.x;
    const int wave = t >> 6;
    const int lane = t & 63;
    int bx = blockIdx.x, by = blockIdx.y;
    remap_block(bx, by);
    const long row0 = (long)by * 128;
    const long col0 = (long)bx * 128;
    const int wr = wave >> 1, wc = wave & 1;

    f32x4 accU[4][4], accV[4][4];
#pragma unroll
    for (int i = 0; i < 4; i++)
#pragma unroll
        for (int j = 0; j < 4; j++) {
            accU[i][j] = f32x4{0.f, 0.f, 0.f, 0.f};
            accV[i][j] = f32x4{0.f, 0.f, 0.f, 0.f};
        }

    const int  q  = t >> 2;
    const int  gp = ((t & 3) + 4 - ((q + (q >> 2)) & 3)) & 3;
    const bf16* gA  = A  + (row0 + q) * 2048 + gp * 8;
    const bf16* gB1 = B1 + (col0 + q) * 2048 + gp * 8;
    const bf16* gB2 = B2 + (col0 + q) * 2048 + gp * 8;

    const int l15  = lane & 15;
    const int fch  = ((lane >> 4) + l15 + (l15 >> 2)) & 3;
    const int aoff = (wr * 64 + l15) * 32 + fch * 8;
    const int boff = (wc * 64 + l15) * 32 + fch * 8;

    auto stage = [&](int buf, int k0) {
        bf16* dA  = sA  + buf * 4096 + wave * 512;
        bf16* dB1 = sB1 + buf * 4096 + wave * 512;
        bf16* dB2 = sB2 + buf * 4096 + wave * 512;
        async_load16(gA  + k0,             dA);
        async_load16(gA  + 64 * 2048 + k0, dA + 2048);
        async_load16(gB1 + k0,             dB1);
        async_load16(gB1 + 64 * 2048 + k0, dB1 + 2048);
        async_load16(gB2 + k0,             dB2);
        async_load16(gB2 + 64 * 2048 + k0, dB2 + 2048);
    };

    stage(0, 0);
    __syncthreads();
    for (int k = 0; k < 64; k++) {
        const int cur = k & 1;
        if (k + 1 < 64) stage(cur ^ 1, (k + 1) << 5);

        bf16x8 af[4], b1v[4], b2v[4];
#pragma unroll
        for (int i = 0; i < 4; i++)
            af[i] = *(const bf16x8*)(sA + cur * 4096 + aoff + i * 16 * 32);
#pragma unroll
        for (int j = 0; j < 4; j++) {
            b1v[j] = *(const bf16x8*)(sB1 + cur * 4096 + boff + j * 16 * 32);
            b2v[j] = *(const bf16x8*)(sB2 + cur * 4096 + boff + j * 16 * 32);
        }
#pragma unroll
        for (int i = 0; i < 4; i++)
#pragma unroll
            for (int j = 0; j < 4; j++) {
                accV[i][j] = __builtin_amdgcn_mfma_f32_16x16x32_bf16(
                    af[i], b1v[j], accV[i][j], 0, 0, 0);
                accU[i][j] = __builtin_amdgcn_mfma_f32_16x16x32_bf16(
                    af[i], b2v[j], accU[i][j], 0, 0, 0);
            }
        __syncthreads();
    }

    float* epi = (float*)smem + wave * 1024;
    const int wbase = (lane >> 4) * 256 + (l15 >> 2) * 4 + (l15 & 3);

#pragma unroll
    for (int i = 0; i < 4; i++) {
#pragma unroll
        for (int j = 0; j < 4; j++)
#pragma unroll
            for (int r = 0; r < 4; r++)
                epi[wbase + r * 64 + 16 * j] = accV[i][j][r];
        f32x4 v4[4];
#pragma unroll
        for (int qq = 0; qq < 4; qq++)
            v4[qq] = ((const f32x4*)epi)[qq * 64 + lane];
#pragma unroll
        for (int j = 0; j < 4; j++)
#pragma unroll
            for (int r = 0; r < 4; r++)
                epi[wbase + r * 64 + 16 * j] = accU[i][j][r];

#pragma unroll
        for (int qq = 0; qq < 4; qq++) {
            const f32x4 a4 = ((const f32x4*)epi)[qq * 64 + lane];
            const long m  = row0 + wr * 64 + i * 16 + qq * 4 + (lane >> 4);
            const long n  = col0 + wc * 64 + 4 * l15;
            const long iu = m * 1024 + n;
            const f32x4 u0 = *(const f32x4*)(u + iu);
            const f32x4 c1 = *(const f32x4*)(bl + n);
            const f32x4 c2 = *(const f32x4*)(bn + n);
            f32x4 un; bf16x4 rv, hv;
#pragma unroll
            for (int e = 0; e < 4; e++) {
                un[e] = a4[e] - u0[e] - C_DT * c1[e];
                rv[e] = (bf16)(C_DTEPS * fmaxf(un[e], 0.f) - v4[qq][e]);
                hv[e] = (bf16)(un[e] + C_DT * c2[e]);
            }
            *(f32x4*)(u + iu) = un;
            *(bf16x4*)(ACo + m * 2048 + n)        = rv;
            *(bf16x4*)(ACo + m * 2048 + 1024 + n) = hv;
        }
    }
}

// logits = (Ah+Al)@(Bh+Bl)^T + bias (3-term), fp32 out, double-buffered.
__global__ __launch_bounds__(256, 2)
void gemm_split(const bf16* __restrict__ Ah, const bf16* __restrict__ Al,
                const bf16* __restrict__ Bh, const bf16* __restrict__ Bl,
                float* __restrict__ out, const float* __restrict__ bias,
                int M, int N, int K, int blim)
{
    __shared__ __attribute__((aligned(16))) char smem[65536];
    bf16* sAh = (bf16*)smem;
    bf16* sAl = (bf16*)(smem + 16384);
    bf16* sBh = (bf16*)(smem + 32768);
    bf16* sBl = (bf16*)(smem + 49152);

    const int t    = threadIdx.x;
    const int wave = t >> 6;
    const int lane = t & 63;
    int bx = blockIdx.x, by = blockIdx.y;
    remap_block(bx, by);
    const long row0 = (long)by * 128;
    const long col0 = (long)bx * 128;
    const int wr = wave >> 1, wc = wave & 1;

    f32x4 acc[4][4];
#pragma unroll
    for (int i = 0; i < 4; i++)
#pragma unroll
        for (int j = 0; j < 4; j++)
            acc[i][j] = f32x4{0.f, 0.f, 0.f, 0.f};

    const int  q  = t >> 2;
    const int  gp = ((t & 3) + 4 - ((q + (q >> 2)) & 3)) & 3;
    const long gao = (row0 + q) * (long)K + gp * 8;
    const long gbo = (col0 + q) * (long)K + gp * 8;

    const int l15  = lane & 15;
    const int fch  = ((lane >> 4) + l15 + (l15 >> 2)) & 3;
    const int aoff = (wr * 64 + l15) * 32 + fch * 8;
    const int boff = (wc * 64 + l15) * 32 + fch * 8;

    auto stage = [&](int buf, int k0) {
        const int d = buf * 4096 + wave * 512;
        async_load16(Ah + gao + k0,                 sAh + d);
        async_load16(Ah + gao + 64 * (long)K + k0,  sAh + d + 2048);
        async_load16(Al + gao + k0,                 sAl + d);
        async_load16(Al + gao + 64 * (long)K + k0,  sAl + d + 2048);
        async_load16(Bh + gbo + k0,                 sBh + d);
        async_load16(Bh + gbo + 64 * (long)K + k0,  sBh + d + 2048);
        async_load16(Bl + gbo + k0,                 sBl + d);
        async_load16(Bl + gbo + 64 * (long)K + k0,  sBl + d + 2048);
    };

    const int nIter = K >> 5;
    stage(0, 0);
    __syncthreads();
    for (int k = 0; k < nIter; k++) {
        const int cur = k & 1;
        if (k + 1 < nIter) stage(cur ^ 1, (k + 1) << 5);

        bf16x8 ah[4], al[4], bh[4], bl[4];
#pragma unroll
        for (int i = 0; i < 4; i++) {
            ah[i] = *(const bf16x8*)(sAh + cur * 4096 + aoff + i * 16 * 32);
            al[i] = *(const bf16x8*)(sAl + cur * 4096 + aoff + i * 16 * 32);
        }
#pragma unroll
        for (int j = 0; j < 4; j++) {
            bh[j] = *(const bf16x8*)(sBh + cur * 4096 + boff + j * 16 * 32);
            bl[j] = *(const bf16x8*)(sBl + cur * 4096 + boff + j * 16 * 32);
        }
#pragma unroll
        for (int i = 0; i < 4; i++)
#pragma unroll
            for (int j = 0; j < 4; j++) {
                acc[i][j] = __builtin_amdgcn_mfma_f32_16x16x32_bf16(
                    ah[i], bh[j], acc[i][j], 0, 0, 0);
                acc[i][j] = __builtin_amdgcn_mfma_f32_16x16x32_bf16(
                    ah[i], bl[j], acc[i][j], 0, 0, 0);
                acc[i][j] = __builtin_amdgcn_mfma_f32_16x16x32_bf16(
                    al[i], bh[j], acc[i][j], 0, 0, 0);
            }
        __syncthreads();
    }

    float* epi = (float*)smem + wave * 1024;
    const int wbase = (lane >> 4) * 256 + (l15 >> 2) * 4 + (l15 & 3);

#pragma unroll
    for (int i = 0; i < 4; i++) {
#pragma unroll
        for (int j = 0; j < 4; j++)
#pragma unroll
            for (int r = 0; r < 4; r++)
                epi[wbase + r * 64 + 16 * j] = acc[i][j][r];

#pragma unroll
        for (int qq = 0; qq < 4; qq++) {
            f32x4 a4 = ((const f32x4*)epi)[qq * 64 + lane];
            const long m = row0 + wr * 64 + i * 16 + qq * 4 + (lane >> 4);
            const long n = col0 + wc * 64 + 4 * l15;
            f32x4 bv = f32x4{0.f, 0.f, 0.f, 0.f};
            if (n < blim) bv = *(const f32x4*)(bias + n);
#pragma unroll
            for (int e = 0; e < 4; e++) a4[e] += bv[e];
            *(f32x4*)(out + m * (long)N + n) = a4;
        }
    }
}

// ---------------------------------------------------------------------------
// Fused prep: x conv (16384 blks) | W_in conv (2048) | W_out hi/lo (1024) |
// W1-3 bf16 + transpose (3072). One dispatch.
// ---------------------------------------------------------------------------
__global__ __launch_bounds__(256)
void prep_all(const float* __restrict__ x, bf16* __restrict__ xb,
              const float* __restrict__ win, bf16* __restrict__ winb,
              const float* __restrict__ wout, bf16* __restrict__ wouth,
              bf16* __restrict__ woutl,
              const float* __restrict__ w0, const float* __restrict__ w1,
              const float* __restrict__ w2,
              bf16* __restrict__ Wb, bf16* __restrict__ Wtb)
{
    __shared__ float tile[32][33];
    const long bid = blockIdx.x;
    const int  t   = threadIdx.x;

    if (bid < 16384) {                         // x fp32 -> bf16
        const long i4 = bid * 256 + t;
        const f32x4 v = ((const f32x4*)x)[i4];
        bf16x4 o;
#pragma unroll
        for (int e = 0; e < 4; e++) o[e] = (bf16)v[e];
        ((bf16x4*)xb)[i4] = o;
    } else if (bid < 18432) {                  // W_in fp32 -> bf16
        const long i4 = (bid - 16384) * 256 + t;
        const f32x4 v = ((const f32x4*)win)[i4];
        bf16x4 o;
#pragma unroll
        for (int e = 0; e < 4; e++) o[e] = (bf16)v[e];
        ((bf16x4*)winb)[i4] = o;
    } else if (bid < 19456) {                  // W_out -> hi/lo, pad to 1024 rows
        const long i4   = (bid - 18432) * 256 + t;
        const long base = i4 * 4;
        const int  nrow = (int)(base >> 10);
        bf16x4 h, l;
        if (nrow < 1000) {
            const f32x4 v = ((const f32x4*)wout)[i4];
#pragma unroll
            for (int e = 0; e < 4; e++) {
                bf16 hh = (bf16)v[e];
                h[e] = hh;
                l[e] = (bf16)(v[e] - (float)hh);
            }
        } else {
#pragma unroll
            for (int e = 0; e < 4; e++) { h[e] = (bf16)0.f; l[e] = (bf16)0.f; }
        }
        ((bf16x4*)wouth)[i4] = h;
        ((bf16x4*)woutl)[i4] = l;
    } else {                                   // W1-3 bf16 + transpose
        const long b2 = bid - 19456;
        const int  z  = (int)(b2 >> 10);
        const int  idx = (int)(b2 & 1023);
        const float* W = (z == 0) ? w0 : (z == 1) ? w1 : w2;
        const long zo = (long)z << 20;
        const int bxt = (idx & 31) * 32, byt = (idx >> 5) * 32;
        const int tx = t & 31, ty = t >> 5;
#pragma unroll
        for (int i = 0; i < 32; i += 8) {
            float v = W[(long)(byt + ty + i) * 1024 + bxt + tx];
            tile[ty + i][tx] = v;
            Wb[zo + (long)(byt + ty + i) * 1024 + bxt + tx] = (bf16)v;
        }
        __syncthreads();
#pragma unroll
        for (int i = 0; i < 32; i += 8)
            Wtb[zo + (long)(bxt + ty + i) * 1024 + byt + tx] = (bf16)tile[tx][ty + i];
    }
}

__global__ __launch_bounds__(256)
void softmax_rows(const float* __restrict__ logits, float* __restrict__ out)
{
    const int row = blockIdx.x;
    const float* lp = logits + (long)row * 1024;
    const int t = threadIdx.x;
    float v[4];
    float mx = -1e30f;
#pragma unroll
    for (int i = 0; i < 4; i++) {
        const int c = t + i * 256;
        v[i] = (c < 1000) ? lp[c] : -1e30f;
        mx = fmaxf(mx, v[i]);
    }
#pragma unroll
    for (int off = 32; off; off >>= 1)
        mx = fmaxf(mx, __shfl_xor(mx, off));
    __shared__ float sm[4], ss[4];
    const int wave = t >> 6;
    if ((t & 63) == 0) sm[wave] = mx;
    __syncthreads();
    mx = fmaxf(fmaxf(sm[0], sm[1]), fmaxf(sm[2], sm[3]));
    float sum = 0.f;
#pragma unroll
    for (int i = 0; i < 4; i++) {
        v[i] = __expf(v[i] - mx);
        sum += v[i];
    }
#pragma unroll
    for (int off = 32; off; off >>= 1)
        sum += __shfl_xor(sum, off);
    if ((t & 63) == 0) ss[wave] = sum;
    __syncthreads();
    const float inv = 1.f / (ss[0] + ss[1] + ss[2] + ss[3]);
#pragma unroll
    for (int i = 0; i < 4; i++) {
        const int c = t + i * 256;
        if (c < 1000) out[(long)row * 1000 + c] = v[i] * inv;
    }
}

extern "C" void kernel_launch(void* const* d_in, const int* in_sizes, int n_in,
                              void* d_out, int out_size, void* d_ws, size_t ws_size,
                              hipStream_t stream)
{
    const float* x     = (const float*)d_in[0];
    const float* W_in  = (const float*)d_in[1];
    const float* b_in  = (const float*)d_in[2];
    const float* Ws[3] = {(const float*)d_in[3], (const float*)d_in[5], (const float*)d_in[7]};
    const float* bs[3] = {(const float*)d_in[4], (const float*)d_in[6], (const float*)d_in[8]};
    const float* W_out = (const float*)d_in[9];
    const float* b_out = (const float*)d_in[10];
    float* out = (float*)d_out;

    char* ws = (char*)d_ws;
    const size_t MB = 1u << 20;
    const long M1 = 1024L * 1024;
    // Timeline: xb@0..32MB (prep -> z0m); Bcat@18..30 written by pp2b (xb
    //   dead); zh@0/zl@16 by bt<5> (after layers; Bcat dead by then).
    // AC_b region 122..154MB transients: Wtbf@122 (prep->z0m), Minv@128
    //   (z0m->pp2b), Gmat@134 (z0m->pp2b). All dead before layer0's write.
    bf16*  xb    = (bf16*)(ws);             // 32 MB
    bf16*  zh    = (bf16*)(ws);             // 16 MB
    bf16*  zl    = (bf16*)(ws + 16 * MB);   // 16 MB
    bf16*  Bcat  = (bf16*)(ws + 18 * MB);   // 12 MB (3 x 1024x2048; [2] unused)
    bf16*  Winb  = (bf16*)(ws + 32 * MB);   //  4 MB
    bf16*  Wouth = (bf16*)(ws + 36 * MB);   //  2 MB
    bf16*  Woutl = (bf16*)(ws + 38 * MB);   //  2 MB
    bf16*  Wbf   = (bf16*)(ws + 40 * MB);   //  6 MB
    bf16*  Ccat  = (bf16*)(ws + 46 * MB);   // 12 MB (3 x 1024x2048)
    float* u     = (float*)(ws + 58 * MB);  // 32 MB (in-place) -> logits
    float* logits= (float*)(ws + 58 * MB);
    bf16*  AC_a  = (bf16*)(ws + 90 * MB);   // 32 MB
    bf16*  AC_b  = (bf16*)(ws + 122 * MB);  // 32 MB
    bf16*  Wtbf  = (bf16*)(ws + 122 * MB);  //  6 MB transient
    bf16*  Minv  = (bf16*)(ws + 128 * MB);  //  6 MB transient
    bf16*  Gmat  = (bf16*)(ws + 134 * MB);  //  6 MB transient

    const dim3 blk(256);
    const dim3 gBig(8, 64);
    const dim3 gZ0(8, 112);

    // 1: all conversions + transposes
    prep_all<<<22528, blk, 0, stream>>>(x, xb, W_in, Winb, W_out, Wouth, Woutl,
                                        Ws[0], Ws[1], Ws[2], Wbf, Wtbf);

    // 2: z0 (512 blocks) + Minv (192) + G = W@W^T (192) in one dispatch
    gemm_z0m<<<gZ0, blk, 0, stream>>>(xb, Winb, Wtbf, Wbf, u, AC_a,
                                      Minv, Gmat, b_in, bs[0]);

    // 3: pp2b — Bcat (hi copy + lo GEMM, z<2), Ccat-hi = 0.1*W@Minv,
    //    Ccat-lo = SC_G1*G - SC_G2*G@G. 512 independent blocks.
    pp2b<<<512, blk, 0, stream>>>(Minv, Wbf, Gmat, Bcat, Ccat);

    // 4-5: fused layers 0,1 (V in registers only)
    gemm_layer<<<gBig, blk, 0, stream>>>(AC_a, Bcat, Ccat, u, AC_b, bs[0], bs[1]);
    gemm_layer<<<gBig, blk, 0, stream>>>(AC_b, Bcat + 2 * M1, Ccat + 2 * M1,
                                         u, AC_a, bs[1], bs[2]);
    // 6: layer 2 u-only: z = AC_a @ Ccat2^T - u - 0.1*b3 -> zh/zl
    gemm_bt<5><<<gBig, blk, 0, stream>>>(AC_a, Ccat + 4 * M1, nullptr, zh, zl,
                                         u, bs[2], nullptr,
                                         8192, 1024, 2048, 2048, 2048,
                                         1024, 1024, 1024, 1.f, 0, 0, 0, 0);

    // 7-8: logits (3-term split) + softmax
    gemm_split<<<gBig, blk, 0, stream>>>(zh, zl, Wouth, Woutl, logits, b_out,
                                         8192, 1024, 1024, 1000);
    softmax_rows<<<8192, blk, 0, stream>>>(logits, out);
}